// Round 4
// baseline (188.090 us; speedup 1.0000x reference)
//
#include <hip/hip_runtime.h>
#include <hip/hip_bf16.h>
#include <cstdint>
#include <cstddef>

#define BB 4
#define SEQ 2048
#define CD 768
#define NH 12
#define DH 64
#define MROWS (BB*SEQ)      // 8192
#define NQKV (3*CD)         // 2304

typedef float f32x4 __attribute__((ext_vector_type(4)));
typedef float f32x16 __attribute__((ext_vector_type(16)));
typedef short bf16x8 __attribute__((ext_vector_type(8)));

static __device__ __forceinline__ unsigned short f2bf(float f) {
  union { float f; unsigned int u; } cv; cv.f = f;
  unsigned int u = cv.u;
  unsigned int r = (u + 0x7FFFu + ((u >> 16) & 1u)) >> 16;
  return (unsigned short)r;
}

#define GAS __attribute__((address_space(1)))
#define LAS __attribute__((address_space(3)))
static __device__ __forceinline__ void gl2lds16(const void* g, void* l) {
  __builtin_amdgcn_global_load_lds((const GAS void*)g, (LAS void*)l, 16, 0, 0);
}

#define MFMA(a, b, c) __builtin_amdgcn_mfma_f32_16x16x32_bf16((a), (b), (c), 0, 0, 0)
#define MFMA32(a, b, c) __builtin_amdgcn_mfma_f32_32x32x16_bf16((a), (b), (c), 0, 0, 0)
#define PACKBF(dst, x, y) asm("v_cvt_pk_bf16_f32 %0, %1, %2" : "=v"(dst) : "v"(x), "v"(y))

// 0.125 (1/sqrt(Dh)) * log2(e): folded into Q's gamma/beta so softmax uses exp2 directly
#define QSC 0.18033688011112042f

// ---------------- fp32 -> bf16 convert ----------------
__global__ __launch_bounds__(256) void cvt_bf16(const float* __restrict__ in,
                                                unsigned short* __restrict__ out, int n4) {
  int i = blockIdx.x * 256 + threadIdx.x;
  if (i >= n4) return;
  float4 v = reinterpret_cast<const float4*>(in)[i];
  unsigned int lo = (unsigned int)f2bf(v.x) | ((unsigned int)f2bf(v.y) << 16);
  unsigned int hi = (unsigned int)f2bf(v.z) | ((unsigned int)f2bf(v.w) << 16);
  reinterpret_cast<uint2*>(out)[i] = make_uint2(lo, hi);
}

// ---------------- QKV GEMM (128x128 tile, dbuf LDS) + fused bias + LN epilogue ----------------
__global__ __launch_bounds__(256) void qkv_gemm(
    const unsigned short* __restrict__ Xb, const unsigned short* __restrict__ Wb,
    const float* __restrict__ bias,
    const float* __restrict__ qg, const float* __restrict__ qbt,
    const float* __restrict__ kg, const float* __restrict__ kbt,
    unsigned short* __restrict__ Qo, unsigned short* __restrict__ Ko,
    unsigned short* __restrict__ Vo) {
  __shared__ unsigned short As[2][128 * 32];
  __shared__ unsigned short Bs[2][128 * 32];
  const int tid = threadIdx.x;
  const int wave = tid >> 6, lane = tid & 63;
  const int g = lane >> 4, cl = lane & 15;
  const int bm = blockIdx.x, bn = blockIdx.y;
  const int wr = (wave >> 1) * 64, wc = (wave & 1) * 64;

  f32x4 acc[4][4] = {};

  const int kc = (tid & 3) * 8;
  const unsigned short* ag0 = Xb + (size_t)(bm * 128 + (tid >> 2)) * CD + kc;
  const unsigned short* ag1 = ag0 + (size_t)64 * CD;
  const unsigned short* bg0 = Wb + (size_t)(bn * 128 + (tid >> 2)) * CD + kc;
  const unsigned short* bg1 = bg0 + (size_t)64 * CD;

#define QSTAGE(buf, k0)                             \
  do {                                              \
    gl2lds16(ag0 + (k0), &As[buf][tid * 8]);        \
    gl2lds16(ag1 + (k0), &As[buf][tid * 8 + 2048]); \
    gl2lds16(bg0 + (k0), &Bs[buf][tid * 8]);        \
    gl2lds16(bg1 + (k0), &Bs[buf][tid * 8 + 2048]); \
  } while (0)

  QSTAGE(0, 0);
  __syncthreads();
  const int NIT = CD / 32;  // 24
  for (int it = 0; it < NIT; ++it) {
    const int cur = it & 1;
    if (it + 1 < NIT) QSTAGE(cur ^ 1, (it + 1) * 32);
    bf16x8 af[4], bfr[4];
#pragma unroll
    for (int i = 0; i < 4; ++i) af[i] = *(const bf16x8*)&As[cur][(wr + i * 16 + cl) * 32 + g * 8];
#pragma unroll
    for (int j = 0; j < 4; ++j) bfr[j] = *(const bf16x8*)&Bs[cur][(wc + j * 16 + cl) * 32 + g * 8];
#pragma unroll
    for (int i = 0; i < 4; ++i)
#pragma unroll
      for (int j = 0; j < 4; ++j) acc[i][j] = MFMA(af[i], bfr[j], acc[i][j]);
    __syncthreads();
  }
#undef QSTAGE

  const int j0 = bn * 128 + wc;
  const int t = j0 / CD;
  const int h = (j0 % CD) / DH;
  float bia[4], gam[4] = {0, 0, 0, 0}, bet[4] = {0, 0, 0, 0};
#pragma unroll
  for (int j = 0; j < 4; ++j) {
    int d = j * 16 + cl;
    bia[j] = bias[j0 + d];
    if (t == 0) { gam[j] = qg[d] * QSC; bet[j] = qbt[d] * QSC; }  // fold softmax scale into Q
    else if (t == 1) { gam[j] = kg[d]; bet[j] = kbt[d]; }
  }
  unsigned short* Out = (t == 0) ? Qo : (t == 1) ? Ko : Vo;
#pragma unroll
  for (int i = 0; i < 4; ++i) {
#pragma unroll
    for (int r = 0; r < 4; ++r) {
      float vj[4];
#pragma unroll
      for (int j = 0; j < 4; ++j) vj[j] = acc[i][j][r] + bia[j];
      const int m = bm * 128 + wr + i * 16 + g * 4 + r;
      const int b = m >> 11, n = m & 2047;
      size_t base = ((size_t)(b * NH + h) * SEQ + n) * DH;
      if (t < 2) {
        float s = vj[0] + vj[1] + vj[2] + vj[3];
        float ss = vj[0] * vj[0] + vj[1] * vj[1] + vj[2] * vj[2] + vj[3] * vj[3];
#pragma unroll
        for (int msk = 1; msk < 16; msk <<= 1) {
          s += __shfl_xor(s, msk, 64);
          ss += __shfl_xor(ss, msk, 64);
        }
        float mu = s * (1.0f / 64.0f);
        float var = ss * (1.0f / 64.0f) - mu * mu;
        float rstd = rsqrtf(var + 1e-5f);
#pragma unroll
        for (int j = 0; j < 4; ++j)
          Out[base + j * 16 + cl] = f2bf((vj[j] - mu) * rstd * gam[j] + bet[j]);
      } else {
#pragma unroll
        for (int j = 0; j < 4; ++j) Out[base + j * 16 + cl] = f2bf(vj[j]);
      }
    }
  }
}

// ---------------- V transpose: Vo[b,h,n,d] -> Vt[b,h,d,n] ----------------
__global__ __launch_bounds__(256) void transpose_v(const unsigned short* __restrict__ Vo,
                                                   unsigned short* __restrict__ Vt) {
  __shared__ unsigned short t[64 * 65];
  const int bh = blockIdx.y, n0 = blockIdx.x * 64;
  const int tid = threadIdx.x;
  const unsigned short* src = Vo + ((size_t)bh * SEQ + n0) * DH;
  const int r = tid >> 3, c0 = (tid & 7) * 8;
#pragma unroll
  for (int p = 0; p < 2; ++p) {
    bf16x8 v = *(const bf16x8*)&src[(size_t)(r + p * 32) * DH + c0];
#pragma unroll
    for (int j = 0; j < 8; ++j) t[(c0 + j) * 65 + (r + p * 32)] = (unsigned short)v[j];
  }
  __syncthreads();
  const int d = tid >> 2, nq = (tid & 3) * 16;
  unsigned short tmp[16];
#pragma unroll
  for (int j = 0; j < 16; ++j) tmp[j] = t[d * 65 + nq + j];
  unsigned short* dst = Vt + ((size_t)bh * DH + d) * SEQ + n0 + nq;
  *(bf16x8*)&dst[0] = *(const bf16x8*)&tmp[0];
  *(bf16x8*)&dst[8] = *(const bf16x8*)&tmp[8];
}

// ---------------- Flash attention: swapped QK^T, 32x32 MFMA, dbuf LDS, in-register softmax ----------------
// 4 waves x 32 q-rows, KVBLK=64. S^T = mfma(K, Q): lane holds S[key=crow(r,hi)+32ks][q=lane&31].
__global__ __launch_bounds__(256, 3) void attn_fwd(
    const unsigned short* __restrict__ Qb, const unsigned short* __restrict__ Kb,
    const unsigned short* __restrict__ Vtb, unsigned short* __restrict__ Ob) {
  __shared__ unsigned short kl[2][64 * 64];   // [key][d], 128B rows, XOR-swizzled
  __shared__ unsigned short vt[2][64 * 64];   // [d][key], 128B rows, XOR-swizzled
  __shared__ float linv[4][32];
  const int tid = threadIdx.x, wave = tid >> 6, lane = tid & 63;
  const int q32 = lane & 31, hi = lane >> 5;
  const int bh = blockIdx.y;
  const int qbase = blockIdx.x * 128 + wave * 32;

  // Q fragments (B-operand: row=q=lane&31, k = dc*16 + hi*8 + i), pre-scaled by QSC
  const unsigned short* qrow = Qb + ((size_t)bh * SEQ + qbase + q32) * DH + hi * 8;
  bf16x8 qf[4];
#pragma unroll
  for (int dc = 0; dc < 4; ++dc) qf[dc] = *(const bf16x8*)&qrow[dc * 16];

  const unsigned short* Kh = Kb + (size_t)bh * SEQ * DH;
  const unsigned short* Vth = Vtb + (size_t)bh * DH * SEQ;

  const int sr = tid >> 3;
  const int sc = 8 * ((tid & 7) ^ (sr & 7));
  const int ksw = (q32 & 7) << 3;

#define ASTAGE(buf, kb0)                                                      \
  do {                                                                        \
    gl2lds16(&Kh[(size_t)((kb0) + sr) * DH + sc], &kl[buf][tid * 8]);         \
    gl2lds16(&Kh[(size_t)((kb0) + sr + 32) * DH + sc], &kl[buf][tid * 8 + 2048]); \
    gl2lds16(&Vth[(size_t)sr * SEQ + (kb0) + sc], &vt[buf][tid * 8]);         \
    gl2lds16(&Vth[(size_t)(sr + 32) * SEQ + (kb0) + sc], &vt[buf][tid * 8 + 2048]); \
  } while (0)

  f32x16 o0 = {}, o1 = {};
  float m = -__builtin_inff(), l = 0.0f;

  ASTAGE(0, 0);
  __syncthreads();
  const int NT = SEQ / 64;  // 32
  for (int it = 0; it < NT; ++it) {
    const int cur = it & 1;
    if (it + 1 < NT) ASTAGE(cur ^ 1, (it + 1) * 64);

    // S^T = K . Q^T : A = K rows (key), B = Q rows (q)
    f32x16 s0 = {}, s1 = {};
    __builtin_amdgcn_s_setprio(1);
#pragma unroll
    for (int dc = 0; dc < 4; ++dc) {
      const int colb = dc * 16 + hi * 8;
      bf16x8 kf0 = *(const bf16x8*)&kl[cur][q32 * 64 + (colb ^ ksw)];
      bf16x8 kf1 = *(const bf16x8*)&kl[cur][(32 + q32) * 64 + (colb ^ ksw)];
      s0 = MFMA32(kf0, qf[dc], s0);
      s1 = MFMA32(kf1, qf[dc], s1);
    }
    __builtin_amdgcn_s_setprio(0);

    // online softmax, in-register; max via v_max3 tree (depth ~4)
    float pm8[8];
#pragma unroll
    for (int i = 0; i < 8; ++i)
      pm8[i] = fmaxf(fmaxf(s0[2 * i], s0[2 * i + 1]), fmaxf(s1[2 * i], s1[2 * i + 1]));
    float pa_ = fmaxf(fmaxf(pm8[0], pm8[1]), pm8[2]);
    float pb_ = fmaxf(fmaxf(pm8[3], pm8[4]), pm8[5]);
    float pc_ = fmaxf(pm8[6], pm8[7]);
    float vmax = fmaxf(fmaxf(pa_, pb_), pc_);
    vmax = fmaxf(vmax, __shfl_xor(vmax, 32, 64));

    if (!__all(vmax - m <= 11.0f)) {   // defer-max (T13), log2 domain
      float mn = fmaxf(m, vmax);
      float corr = exp2f(m - mn);
      m = mn;
      l *= corr;
#pragma unroll
      for (int r = 0; r < 16; ++r) { o0[r] *= corr; o1[r] *= corr; }
    }

    float su0 = 0.0f, su1 = 0.0f, su2 = 0.0f, su3 = 0.0f;
#pragma unroll
    for (int r = 0; r < 16; r += 4) {
      s0[r] = exp2f(s0[r] - m);     su0 += s0[r];
      s0[r + 1] = exp2f(s0[r + 1] - m); su1 += s0[r + 1];
      s0[r + 2] = exp2f(s0[r + 2] - m); su2 += s0[r + 2];
      s0[r + 3] = exp2f(s0[r + 3] - m); su3 += s0[r + 3];
    }
#pragma unroll
    for (int r = 0; r < 16; r += 4) {
      s1[r] = exp2f(s1[r] - m);     su0 += s1[r];
      s1[r + 1] = exp2f(s1[r + 1] - m); su1 += s1[r + 1];
      s1[r + 2] = exp2f(s1[r + 2] - m); su2 += s1[r + 2];
      s1[r + 3] = exp2f(s1[r + 3] - m); su3 += s1[r + 3];
    }
    float sum = (su0 + su1) + (su2 + su3);
    sum += __shfl_xor(sum, 32, 64);
    l += sum;

    // P -> bf16 A-frags in-register (T12 exchange): pa[c][i] = P[q][key = c*16 + 8*hi + i]
    bf16x8 pav[4];
#pragma unroll
    for (int c = 0; c < 4; ++c) {
      const int b = 8 * (c & 1);
      unsigned int wA0, wA1, wB0, wB1;
      if (c < 2) {
        PACKBF(wA0, s0[b + 0], s0[b + 1]); PACKBF(wA1, s0[b + 2], s0[b + 3]);
        PACKBF(wB0, s0[b + 4], s0[b + 5]); PACKBF(wB1, s0[b + 6], s0[b + 7]);
      } else {
        PACKBF(wA0, s1[b + 0], s1[b + 1]); PACKBF(wA1, s1[b + 2], s1[b + 3]);
        PACKBF(wB0, s1[b + 4], s1[b + 5]); PACKBF(wB1, s1[b + 6], s1[b + 7]);
      }
      unsigned int send0 = hi ? wA0 : wB0;
      unsigned int send1 = hi ? wA1 : wB1;
      unsigned int r0 = (unsigned int)__shfl_xor((int)send0, 32, 64);
      unsigned int r1 = (unsigned int)__shfl_xor((int)send1, 32, 64);
      union { unsigned int w[4]; bf16x8 v; } u;
      u.w[0] = hi ? r0 : wA0;
      u.w[1] = hi ? r1 : wA1;
      u.w[2] = hi ? wB0 : r0;
      u.w[3] = hi ? wB1 : r1;
      pav[c] = u.v;
    }

    // PV: O[q][d] += P[q][key] . V^T[d][key] ; B = V^T rows (d)
    __builtin_amdgcn_s_setprio(1);
#pragma unroll
    for (int c = 0; c < 4; ++c) {
      const int colb = c * 16 + hi * 8;
      bf16x8 vf0 = *(const bf16x8*)&vt[cur][q32 * 64 + (colb ^ ksw)];
      bf16x8 vf1 = *(const bf16x8*)&vt[cur][(32 + q32) * 64 + (colb ^ ksw)];
      o0 = MFMA32(pav[c], vf0, o0);
      o1 = MFMA32(pav[c], vf1, o1);
    }
    __builtin_amdgcn_s_setprio(0);
    __syncthreads();
  }
#undef ASTAGE

  linv[wave][q32] = 1.0f / l;   // hi-pair writes same value
  __syncthreads();
  const int b = bh / NH, h = bh % NH;
#pragma unroll
  for (int r = 0; r < 16; ++r) {
    const int qq = (r & 3) + 8 * (r >> 2) + 4 * hi;   // output row within 32
    float iv = linv[wave][qq];
    size_t base = ((size_t)(b * SEQ + qbase + qq)) * CD + h * DH;
    Ob[base + q32] = f2bf(o0[r] * iv);
    Ob[base + 32 + q32] = f2bf(o1[r] * iv);
  }
}

// ---------------- Proj GEMM (128x128 tile, dbuf LDS) + bias, fp32 out ----------------
__global__ __launch_bounds__(256) void proj_gemm(
    const unsigned short* __restrict__ Ab, const unsigned short* __restrict__ Wb,
    const float* __restrict__ bias, float* __restrict__ out) {
  __shared__ unsigned short As[2][128 * 32];
  __shared__ unsigned short Bs[2][128 * 32];
  const int tid = threadIdx.x;
  const int wave = tid >> 6, lane = tid & 63;
  const int g = lane >> 4, cl = lane & 15;
  const int bm = blockIdx.x, bn = blockIdx.y;
  const int wr = (wave >> 1) * 64, wc = (wave & 1) * 64;

  f32x4 acc[4][4] = {};

  const int kc = (tid & 3) * 8;
  const unsigned short* ag0 = Ab + (size_t)(bm * 128 + (tid >> 2)) * CD + kc;
  const unsigned short* ag1 = ag0 + (size_t)64 * CD;
  const unsigned short* bg0 = Wb + (size_t)(bn * 128 + (tid >> 2)) * CD + kc;
  const unsigned short* bg1 = bg0 + (size_t)64 * CD;

#define PSTAGE(buf, k0)                             \
  do {                                              \
    gl2lds16(ag0 + (k0), &As[buf][tid * 8]);        \
    gl2lds16(ag1 + (k0), &As[buf][tid * 8 + 2048]); \
    gl2lds16(bg0 + (k0), &Bs[buf][tid * 8]);        \
    gl2lds16(bg1 + (k0), &Bs[buf][tid * 8 + 2048]); \
  } while (0)

  PSTAGE(0, 0);
  __syncthreads();
  const int NIT = CD / 32;  // 24
  for (int it = 0; it < NIT; ++it) {
    const int cur = it & 1;
    if (it + 1 < NIT) PSTAGE(cur ^ 1, (it + 1) * 32);
    bf16x8 af[4], bfr[4];
#pragma unroll
    for (int i = 0; i < 4; ++i) af[i] = *(const bf16x8*)&As[cur][(wr + i * 16 + cl) * 32 + g * 8];
#pragma unroll
    for (int j = 0; j < 4; ++j) bfr[j] = *(const bf16x8*)&Bs[cur][(wc + j * 16 + cl) * 32 + g * 8];
#pragma unroll
    for (int i = 0; i < 4; ++i)
#pragma unroll
      for (int j = 0; j < 4; ++j) acc[i][j] = MFMA(af[i], bfr[j], acc[i][j]);
    __syncthreads();
  }
#undef PSTAGE

  const int j0 = bn * 128 + wc;
  float pb4[4];
#pragma unroll
  for (int j = 0; j < 4; ++j) pb4[j] = bias[j0 + j * 16 + cl];
#pragma unroll
  for (int i = 0; i < 4; ++i) {
#pragma unroll
    for (int r = 0; r < 4; ++r) {
      const int m = bm * 128 + wr + i * 16 + g * 4 + r;
      float* orow = out + (size_t)m * CD + j0;
#pragma unroll
      for (int j = 0; j < 4; ++j) orow[j * 16 + cl] = acc[i][j][r] + pb4[j];
    }
  }
}

extern "C" void kernel_launch(void* const* d_in, const int* in_sizes, int n_in,
                              void* d_out, int out_size, void* d_ws, size_t ws_size,
                              hipStream_t stream) {
  const float* x = (const float*)d_in[0];
  const float* qkv_w = (const float*)d_in[1];
  const float* qkv_b = (const float*)d_in[2];
  const float* proj_w = (const float*)d_in[3];
  const float* proj_b = (const float*)d_in[4];
  const float* q_gamma = (const float*)d_in[5];
  const float* q_beta = (const float*)d_in[6];
  const float* k_gamma = (const float*)d_in[7];
  const float* k_beta = (const float*)d_in[8];
  float* out = (float*)d_out;

  char* w = (char*)d_ws;
  unsigned short* Xb = (unsigned short*)w; w += (size_t)MROWS * CD * 2;
  unsigned short* Wq = (unsigned short*)w; w += (size_t)NQKV * CD * 2;
  unsigned short* Wp = (unsigned short*)w; w += (size_t)CD * CD * 2;
  unsigned short* Qo = (unsigned short*)w; w += (size_t)BB * NH * SEQ * DH * 2;
  unsigned short* Ko = (unsigned short*)w; w += (size_t)BB * NH * SEQ * DH * 2;
  unsigned short* Vo = (unsigned short*)w; w += (size_t)BB * NH * SEQ * DH * 2;
  unsigned short* Ob = (unsigned short*)w; w += (size_t)MROWS * CD * 2;
  // Vt reuses the Xb region (dead after qkv_gemm); sizes match exactly.
  unsigned short* Vt = Xb;

  cvt_bf16<<<MROWS * CD / 1024, 256, 0, stream>>>(x, Xb, MROWS * CD / 4);
  cvt_bf16<<<NQKV * CD / 1024, 256, 0, stream>>>(qkv_w, Wq, NQKV * CD / 4);
  cvt_bf16<<<CD * CD / 1024, 256, 0, stream>>>(proj_w, Wp, CD * CD / 4);

  qkv_gemm<<<dim3(MROWS / 128, NQKV / 128), 256, 0, stream>>>(
      Xb, Wq, qkv_b, q_gamma, q_beta, k_gamma, k_beta, Qo, Ko, Vo);

  transpose_v<<<dim3(SEQ / 64, BB * NH), 256, 0, stream>>>(Vo, Vt);

  attn_fwd<<<dim3(SEQ / 128, BB * NH), 256, 0, stream>>>(Qo, Ko, Vt, Ob);

  proj_gemm<<<dim3(MROWS / 128, CD / 128), 256, 0, stream>>>(Ob, Wp, proj_b, out);
}

// Round 5
// 172.510 us; speedup vs baseline: 1.0903x; 1.0903x over previous
//
#include <hip/hip_runtime.h>
#include <hip/hip_bf16.h>
#include <cstdint>
#include <cstddef>

#define BB 4
#define SEQ 2048
#define CD 768
#define NH 12
#define DH 64
#define MROWS (BB*SEQ)      // 8192
#define NQKV (3*CD)         // 2304

typedef float f32x4 __attribute__((ext_vector_type(4)));
typedef float f32x16 __attribute__((ext_vector_type(16)));
typedef short bf16x8 __attribute__((ext_vector_type(8)));

static __device__ __forceinline__ unsigned short f2bf(float f) {
  union { float f; unsigned int u; } cv; cv.f = f;
  unsigned int u = cv.u;
  unsigned int r = (u + 0x7FFFu + ((u >> 16) & 1u)) >> 16;
  return (unsigned short)r;
}

#define GAS __attribute__((address_space(1)))
#define LAS __attribute__((address_space(3)))
static __device__ __forceinline__ void gl2lds16(const void* g, void* l) {
  __builtin_amdgcn_global_load_lds((const GAS void*)g, (LAS void*)l, 16, 0, 0);
}

#define MFMA(a, b, c) __builtin_amdgcn_mfma_f32_16x16x32_bf16((a), (b), (c), 0, 0, 0)
#define MFMA32(a, b, c) __builtin_amdgcn_mfma_f32_32x32x16_bf16((a), (b), (c), 0, 0, 0)
#define PACKBF(dst, x, y) asm("v_cvt_pk_bf16_f32 %0, %1, %2" : "=v"(dst) : "v"(x), "v"(y))
// v_permlane32_swap_b32 a, b: a'[hi]=b[lo-partner], b'[lo]=a[hi-partner]; a,b both updated.
#define SWAP32(a, b) asm("v_permlane32_swap_b32 %0, %1" : "+v"(a), "+v"(b))

// 0.125 (1/sqrt(Dh)) * log2(e): folded into Q's gamma/beta so softmax uses exp2 directly.
// With LN'd q,k: |score_log2| <= 0.1803*|q||k| = 0.1803*64 = 11.5 -> exp2 never overflows,
// so softmax needs NO max subtraction (shift-invariant).
#define QSC 0.18033688011112042f

// ---------------- fp32 -> bf16 convert ----------------
__global__ __launch_bounds__(256) void cvt_bf16(const float* __restrict__ in,
                                                unsigned short* __restrict__ out, int n4) {
  int i = blockIdx.x * 256 + threadIdx.x;
  if (i >= n4) return;
  float4 v = reinterpret_cast<const float4*>(in)[i];
  unsigned int lo = (unsigned int)f2bf(v.x) | ((unsigned int)f2bf(v.y) << 16);
  unsigned int hi = (unsigned int)f2bf(v.z) | ((unsigned int)f2bf(v.w) << 16);
  reinterpret_cast<uint2*>(out)[i] = make_uint2(lo, hi);
}

// ---------------- QKV GEMM (128x128 tile, dbuf LDS) + fused bias + LN epilogue ----------------
__global__ __launch_bounds__(256) void qkv_gemm(
    const unsigned short* __restrict__ Xb, const unsigned short* __restrict__ Wb,
    const float* __restrict__ bias,
    const float* __restrict__ qg, const float* __restrict__ qbt,
    const float* __restrict__ kg, const float* __restrict__ kbt,
    unsigned short* __restrict__ Qo, unsigned short* __restrict__ Ko,
    unsigned short* __restrict__ Vo) {
  __shared__ unsigned short As[2][128 * 32];
  __shared__ unsigned short Bs[2][128 * 32];
  const int tid = threadIdx.x;
  const int wave = tid >> 6, lane = tid & 63;
  const int g = lane >> 4, cl = lane & 15;
  const int bm = blockIdx.x, bn = blockIdx.y;
  const int wr = (wave >> 1) * 64, wc = (wave & 1) * 64;

  f32x4 acc[4][4] = {};

  const int kc = (tid & 3) * 8;
  const unsigned short* ag0 = Xb + (size_t)(bm * 128 + (tid >> 2)) * CD + kc;
  const unsigned short* ag1 = ag0 + (size_t)64 * CD;
  const unsigned short* bg0 = Wb + (size_t)(bn * 128 + (tid >> 2)) * CD + kc;
  const unsigned short* bg1 = bg0 + (size_t)64 * CD;

#define QSTAGE(buf, k0)                             \
  do {                                              \
    gl2lds16(ag0 + (k0), &As[buf][tid * 8]);        \
    gl2lds16(ag1 + (k0), &As[buf][tid * 8 + 2048]); \
    gl2lds16(bg0 + (k0), &Bs[buf][tid * 8]);        \
    gl2lds16(bg1 + (k0), &Bs[buf][tid * 8 + 2048]); \
  } while (0)

  QSTAGE(0, 0);
  __syncthreads();
  const int NIT = CD / 32;  // 24
  for (int it = 0; it < NIT; ++it) {
    const int cur = it & 1;
    if (it + 1 < NIT) QSTAGE(cur ^ 1, (it + 1) * 32);
    bf16x8 af[4], bfr[4];
#pragma unroll
    for (int i = 0; i < 4; ++i) af[i] = *(const bf16x8*)&As[cur][(wr + i * 16 + cl) * 32 + g * 8];
#pragma unroll
    for (int j = 0; j < 4; ++j) bfr[j] = *(const bf16x8*)&Bs[cur][(wc + j * 16 + cl) * 32 + g * 8];
#pragma unroll
    for (int i = 0; i < 4; ++i)
#pragma unroll
      for (int j = 0; j < 4; ++j) acc[i][j] = MFMA(af[i], bfr[j], acc[i][j]);
    __syncthreads();
  }
#undef QSTAGE

  const int j0 = bn * 128 + wc;
  const int t = j0 / CD;
  const int h = (j0 % CD) / DH;
  float bia[4], gam[4] = {0, 0, 0, 0}, bet[4] = {0, 0, 0, 0};
#pragma unroll
  for (int j = 0; j < 4; ++j) {
    int d = j * 16 + cl;
    bia[j] = bias[j0 + d];
    if (t == 0) { gam[j] = qg[d] * QSC; bet[j] = qbt[d] * QSC; }  // fold softmax scale into Q
    else if (t == 1) { gam[j] = kg[d]; bet[j] = kbt[d]; }
  }
  unsigned short* Out = (t == 0) ? Qo : (t == 1) ? Ko : Vo;
#pragma unroll
  for (int i = 0; i < 4; ++i) {
#pragma unroll
    for (int r = 0; r < 4; ++r) {
      float vj[4];
#pragma unroll
      for (int j = 0; j < 4; ++j) vj[j] = acc[i][j][r] + bia[j];
      const int m = bm * 128 + wr + i * 16 + g * 4 + r;
      const int b = m >> 11, n = m & 2047;
      size_t base = ((size_t)(b * NH + h) * SEQ + n) * DH;
      if (t < 2) {
        float s = vj[0] + vj[1] + vj[2] + vj[3];
        float ss = vj[0] * vj[0] + vj[1] * vj[1] + vj[2] * vj[2] + vj[3] * vj[3];
#pragma unroll
        for (int msk = 1; msk < 16; msk <<= 1) {
          s += __shfl_xor(s, msk, 64);
          ss += __shfl_xor(ss, msk, 64);
        }
        float mu = s * (1.0f / 64.0f);
        float var = ss * (1.0f / 64.0f) - mu * mu;
        float rstd = rsqrtf(var + 1e-5f);
#pragma unroll
        for (int j = 0; j < 4; ++j)
          Out[base + j * 16 + cl] = f2bf((vj[j] - mu) * rstd * gam[j] + bet[j]);
      } else {
#pragma unroll
        for (int j = 0; j < 4; ++j) Out[base + j * 16 + cl] = f2bf(vj[j]);
      }
    }
  }
}

// ---------------- V transpose: Vo[b,h,n,d] -> Vt[b,h,d,n] ----------------
__global__ __launch_bounds__(256) void transpose_v(const unsigned short* __restrict__ Vo,
                                                   unsigned short* __restrict__ Vt) {
  __shared__ unsigned short t[64 * 65];
  const int bh = blockIdx.y, n0 = blockIdx.x * 64;
  const int tid = threadIdx.x;
  const unsigned short* src = Vo + ((size_t)bh * SEQ + n0) * DH;
  const int r = tid >> 3, c0 = (tid & 7) * 8;
#pragma unroll
  for (int p = 0; p < 2; ++p) {
    bf16x8 v = *(const bf16x8*)&src[(size_t)(r + p * 32) * DH + c0];
#pragma unroll
    for (int j = 0; j < 8; ++j) t[(c0 + j) * 65 + (r + p * 32)] = (unsigned short)v[j];
  }
  __syncthreads();
  const int d = tid >> 2, nq = (tid & 3) * 16;
  unsigned short tmp[16];
#pragma unroll
  for (int j = 0; j < 16; ++j) tmp[j] = t[d * 65 + nq + j];
  unsigned short* dst = Vt + ((size_t)bh * DH + d) * SEQ + n0 + nq;
  *(bf16x8*)&dst[0] = *(const bf16x8*)&tmp[0];
  *(bf16x8*)&dst[8] = *(const bf16x8*)&tmp[8];
}

// ---------------- Flash attention: swapped QK^T, 32x32 MFMA, no-max softmax ----------------
// 4 waves x 32 q-rows, KVBLK=64. S^T = mfma(K, Q): lane holds S[key=crow(r,hi)+32ks][q=lane&31],
// crow(r,hi) = (r&3) + 8*(r>>2) + 4*hi. No max subtraction (scores bounded, see QSC note).
// Row-sum l computed by ones-MFMA into ol (lane holds l for its own 16 output rows).
__global__ __launch_bounds__(256, 3) void attn_fwd(
    const unsigned short* __restrict__ Qb, const unsigned short* __restrict__ Kb,
    const unsigned short* __restrict__ Vtb, unsigned short* __restrict__ Ob) {
  __shared__ unsigned short kl[2][64 * 64];   // [key][d], 128B rows, XOR-swizzled
  __shared__ unsigned short vt[2][64 * 64];   // [d][key], 128B rows, XOR-swizzled
  const int tid = threadIdx.x, wave = tid >> 6, lane = tid & 63;
  const int q32 = lane & 31, hi = lane >> 5;
  const int bh = blockIdx.y;
  const int qbase = blockIdx.x * 128 + wave * 32;

  // Q fragments (B-operand: row=q=lane&31, k = dc*16 + hi*8 + i), pre-scaled by QSC*gamma
  const unsigned short* qrow = Qb + ((size_t)bh * SEQ + qbase + q32) * DH + hi * 8;
  bf16x8 qf[4];
#pragma unroll
  for (int dc = 0; dc < 4; ++dc) qf[dc] = *(const bf16x8*)&qrow[dc * 16];

  const unsigned short* Kh = Kb + (size_t)bh * SEQ * DH;
  const unsigned short* Vth = Vtb + (size_t)bh * DH * SEQ;

  const int sr = tid >> 3;
  const int sc = 8 * ((tid & 7) ^ (sr & 7));
  const int ksw = (q32 & 7) << 3;

  const short oneb = (short)0x3F80;  // bf16 1.0
  const bf16x8 onesv = {oneb, oneb, oneb, oneb, oneb, oneb, oneb, oneb};

#define ASTAGE(buf, kb0)                                                      \
  do {                                                                        \
    gl2lds16(&Kh[(size_t)((kb0) + sr) * DH + sc], &kl[buf][tid * 8]);         \
    gl2lds16(&Kh[(size_t)((kb0) + sr + 32) * DH + sc], &kl[buf][tid * 8 + 2048]); \
    gl2lds16(&Vth[(size_t)sr * SEQ + (kb0) + sc], &vt[buf][tid * 8]);         \
    gl2lds16(&Vth[(size_t)(sr + 32) * SEQ + (kb0) + sc], &vt[buf][tid * 8 + 2048]); \
  } while (0)

  f32x16 o0 = {}, o1 = {}, ol = {};

  ASTAGE(0, 0);
  __syncthreads();
  const int NT = SEQ / 64;  // 32
#pragma unroll 2
  for (int it = 0; it < NT; ++it) {
    const int cur = it & 1;
    if (it + 1 < NT) ASTAGE(cur ^ 1, (it + 1) * 64);

    // S^T = K . Q^T : A = K rows (key), B = Q rows (q)
    f32x16 s0 = {}, s1 = {};
    __builtin_amdgcn_s_setprio(1);
#pragma unroll
    for (int dc = 0; dc < 4; ++dc) {
      const int colb = dc * 16 + hi * 8;
      bf16x8 kf0 = *(const bf16x8*)&kl[cur][q32 * 64 + (colb ^ ksw)];
      bf16x8 kf1 = *(const bf16x8*)&kl[cur][(32 + q32) * 64 + (colb ^ ksw)];
      s0 = MFMA32(kf0, qf[dc], s0);
      s1 = MFMA32(kf1, qf[dc], s1);
    }
    __builtin_amdgcn_s_setprio(0);

    // P = exp2(S) directly: scores bounded (<= 11.5 in log2 domain), no max needed
#pragma unroll
    for (int r = 0; r < 16; ++r) {
      s0[r] = exp2f(s0[r]);
      s1[r] = exp2f(s1[r]);
    }

    // P -> bf16 A-frags in-register: pav[c][i] = P[q][key = c*16 + 8*hi + i]
    // {w0,w2} = permlane32_swap(wA, wB) gives both halves with zero cndmask.
    bf16x8 pav[4];
#pragma unroll
    for (int c = 0; c < 4; ++c) {
      const int b = 8 * (c & 1);
      unsigned int wA0, wA1, wB0, wB1;
      if (c < 2) {
        PACKBF(wA0, s0[b + 0], s0[b + 1]); PACKBF(wA1, s0[b + 2], s0[b + 3]);
        PACKBF(wB0, s0[b + 4], s0[b + 5]); PACKBF(wB1, s0[b + 6], s0[b + 7]);
      } else {
        PACKBF(wA0, s1[b + 0], s1[b + 1]); PACKBF(wA1, s1[b + 2], s1[b + 3]);
        PACKBF(wB0, s1[b + 4], s1[b + 5]); PACKBF(wB1, s1[b + 6], s1[b + 7]);
      }
      SWAP32(wA0, wB0);  // wA0 -> word0, wB0 -> word2
      SWAP32(wA1, wB1);  // wA1 -> word1, wB1 -> word3
      union { unsigned int w[4]; bf16x8 v; } u;
      u.w[0] = wA0; u.w[1] = wA1; u.w[2] = wB0; u.w[3] = wB1;
      pav[c] = u.v;
    }

    // PV: O[q][d] += P[q][key] . V^T[d][key]; row-sum l via ones-MFMA
    __builtin_amdgcn_s_setprio(1);
#pragma unroll
    for (int c = 0; c < 4; ++c) {
      const int colb = c * 16 + hi * 8;
      bf16x8 vf0 = *(const bf16x8*)&vt[cur][q32 * 64 + (colb ^ ksw)];
      bf16x8 vf1 = *(const bf16x8*)&vt[cur][(32 + q32) * 64 + (colb ^ ksw)];
      o0 = MFMA32(pav[c], vf0, o0);
      o1 = MFMA32(pav[c], vf1, o1);
      ol = MFMA32(pav[c], onesv, ol);
    }
    __builtin_amdgcn_s_setprio(0);
    __syncthreads();
  }
#undef ASTAGE

  const int b = bh / NH, h = bh % NH;
#pragma unroll
  for (int r = 0; r < 16; ++r) {
    const int qq = (r & 3) + 8 * (r >> 2) + 4 * hi;   // output row within 32
    const float iv = __builtin_amdgcn_rcpf(ol[r]);    // ol[r] = l for row qq
    size_t base = ((size_t)(b * SEQ + qbase + qq)) * CD + h * DH;
    Ob[base + q32] = f2bf(o0[r] * iv);
    Ob[base + 32 + q32] = f2bf(o1[r] * iv);
  }
}

// ---------------- Proj GEMM (128x128 tile, dbuf LDS) + bias, fp32 out ----------------
__global__ __launch_bounds__(256) void proj_gemm(
    const unsigned short* __restrict__ Ab, const unsigned short* __restrict__ Wb,
    const float* __restrict__ bias, float* __restrict__ out) {
  __shared__ unsigned short As[2][128 * 32];
  __shared__ unsigned short Bs[2][128 * 32];
  const int tid = threadIdx.x;
  const int wave = tid >> 6, lane = tid & 63;
  const int g = lane >> 4, cl = lane & 15;
  const int bm = blockIdx.x, bn = blockIdx.y;
  const int wr = (wave >> 1) * 64, wc = (wave & 1) * 64;

  f32x4 acc[4][4] = {};

  const int kc = (tid & 3) * 8;
  const unsigned short* ag0 = Ab + (size_t)(bm * 128 + (tid >> 2)) * CD + kc;
  const unsigned short* ag1 = ag0 + (size_t)64 * CD;
  const unsigned short* bg0 = Wb + (size_t)(bn * 128 + (tid >> 2)) * CD + kc;
  const unsigned short* bg1 = bg0 + (size_t)64 * CD;

#define PSTAGE(buf, k0)                             \
  do {                                              \
    gl2lds16(ag0 + (k0), &As[buf][tid * 8]);        \
    gl2lds16(ag1 + (k0), &As[buf][tid * 8 + 2048]); \
    gl2lds16(bg0 + (k0), &Bs[buf][tid * 8]);        \
    gl2lds16(bg1 + (k0), &Bs[buf][tid * 8 + 2048]); \
  } while (0)

  PSTAGE(0, 0);
  __syncthreads();
  const int NIT = CD / 32;  // 24
  for (int it = 0; it < NIT; ++it) {
    const int cur = it & 1;
    if (it + 1 < NIT) PSTAGE(cur ^ 1, (it + 1) * 32);
    bf16x8 af[4], bfr[4];
#pragma unroll
    for (int i = 0; i < 4; ++i) af[i] = *(const bf16x8*)&As[cur][(wr + i * 16 + cl) * 32 + g * 8];
#pragma unroll
    for (int j = 0; j < 4; ++j) bfr[j] = *(const bf16x8*)&Bs[cur][(wc + j * 16 + cl) * 32 + g * 8];
#pragma unroll
    for (int i = 0; i < 4; ++i)
#pragma unroll
      for (int j = 0; j < 4; ++j) acc[i][j] = MFMA(af[i], bfr[j], acc[i][j]);
    __syncthreads();
  }
#undef PSTAGE

  const int j0 = bn * 128 + wc;
  float pb4[4];
#pragma unroll
  for (int j = 0; j < 4; ++j) pb4[j] = bias[j0 + j * 16 + cl];
#pragma unroll
  for (int i = 0; i < 4; ++i) {
#pragma unroll
    for (int r = 0; r < 4; ++r) {
      const int m = bm * 128 + wr + i * 16 + g * 4 + r;
      float* orow = out + (size_t)m * CD + j0;
#pragma unroll
      for (int j = 0; j < 4; ++j) orow[j * 16 + cl] = acc[i][j][r] + pb4[j];
    }
  }
}

extern "C" void kernel_launch(void* const* d_in, const int* in_sizes, int n_in,
                              void* d_out, int out_size, void* d_ws, size_t ws_size,
                              hipStream_t stream) {
  const float* x = (const float*)d_in[0];
  const float* qkv_w = (const float*)d_in[1];
  const float* qkv_b = (const float*)d_in[2];
  const float* proj_w = (const float*)d_in[3];
  const float* proj_b = (const float*)d_in[4];
  const float* q_gamma = (const float*)d_in[5];
  const float* q_beta = (const float*)d_in[6];
  const float* k_gamma = (const float*)d_in[7];
  const float* k_beta = (const float*)d_in[8];
  float* out = (float*)d_out;

  char* w = (char*)d_ws;
  unsigned short* Xb = (unsigned short*)w; w += (size_t)MROWS * CD * 2;
  unsigned short* Wq = (unsigned short*)w; w += (size_t)NQKV * CD * 2;
  unsigned short* Wp = (unsigned short*)w; w += (size_t)CD * CD * 2;
  unsigned short* Qo = (unsigned short*)w; w += (size_t)BB * NH * SEQ * DH * 2;
  unsigned short* Ko = (unsigned short*)w; w += (size_t)BB * NH * SEQ * DH * 2;
  unsigned short* Vo = (unsigned short*)w; w += (size_t)BB * NH * SEQ * DH * 2;
  unsigned short* Ob = (unsigned short*)w; w += (size_t)MROWS * CD * 2;
  // Vt reuses the Xb region (dead after qkv_gemm); sizes match exactly.
  unsigned short* Vt = Xb;

  cvt_bf16<<<MROWS * CD / 1024, 256, 0, stream>>>(x, Xb, MROWS * CD / 4);
  cvt_bf16<<<NQKV * CD / 1024, 256, 0, stream>>>(qkv_w, Wq, NQKV * CD / 4);
  cvt_bf16<<<CD * CD / 1024, 256, 0, stream>>>(proj_w, Wp, CD * CD / 4);

  qkv_gemm<<<dim3(MROWS / 128, NQKV / 128), 256, 0, stream>>>(
      Xb, Wq, qkv_b, q_gamma, q_beta, k_gamma, k_beta, Qo, Ko, Vo);

  transpose_v<<<dim3(SEQ / 64, BB * NH), 256, 0, stream>>>(Vo, Vt);

  attn_fwd<<<dim3(SEQ / 128, BB * NH), 256, 0, stream>>>(Qo, Ko, Vt, Ob);

  proj_gemm<<<dim3(MROWS / 128, CD / 128), 256, 0, stream>>>(Ob, Wp, proj_b, out);
}

// Round 6
// 161.856 us; speedup vs baseline: 1.1621x; 1.0658x over previous
//
#include <hip/hip_runtime.h>
#include <hip/hip_bf16.h>
#include <cstdint>
#include <cstddef>

#define BB 4
#define SEQ 2048
#define CD 768
#define NH 12
#define DH 64
#define MROWS (BB*SEQ)      // 8192
#define NQKV (3*CD)         // 2304

typedef float f32x4 __attribute__((ext_vector_type(4)));
typedef float f32x16 __attribute__((ext_vector_type(16)));
typedef short bf16x8 __attribute__((ext_vector_type(8)));

static __device__ __forceinline__ unsigned short f2bf(float f) {
  union { float f; unsigned int u; } cv; cv.f = f;
  unsigned int u = cv.u;
  unsigned int r = (u + 0x7FFFu + ((u >> 16) & 1u)) >> 16;
  return (unsigned short)r;
}

// raw v_exp_f32: our exponents are bounded (|x| <= ~23), no OCML denorm/overflow fixups needed
static __device__ __forceinline__ float fexp2(float x) {
#if __has_builtin(__builtin_amdgcn_exp2f)
  return __builtin_amdgcn_exp2f(x);
#else
  float r; asm("v_exp_f32 %0, %1" : "=v"(r) : "v"(x)); return r;
#endif
}

#define GAS __attribute__((address_space(1)))
#define LAS __attribute__((address_space(3)))
static __device__ __forceinline__ void gl2lds16(const void* g, void* l) {
  __builtin_amdgcn_global_load_lds((const GAS void*)g, (LAS void*)l, 16, 0, 0);
}

#define MFMA(a, b, c) __builtin_amdgcn_mfma_f32_16x16x32_bf16((a), (b), (c), 0, 0, 0)
#define MFMA32(a, b, c) __builtin_amdgcn_mfma_f32_32x32x16_bf16((a), (b), (c), 0, 0, 0)
#define PACKBF(dst, x, y) asm("v_cvt_pk_bf16_f32 %0, %1, %2" : "=v"(dst) : "v"(x), "v"(y))
// v_permlane32_swap_b32 a, b: exchanges a's hi-half lanes with b's lo-half lanes.
#define SWAP32(a, b) asm("v_permlane32_swap_b32 %0, %1" : "+v"(a), "+v"(b))

// 0.125 (1/sqrt(Dh)) * log2(e): folded into Q's gamma/beta so softmax uses exp2 directly.
// With LN'd q,k: |score_log2| <= 0.1803*|q||k| = 0.1803*64 = 11.5 -> exp2 never overflows,
// so softmax needs NO max subtraction (shift-invariant).
#define QSC 0.18033688011112042f

// ---------------- fp32 -> bf16 convert ----------------
__global__ __launch_bounds__(256) void cvt_bf16(const float* __restrict__ in,
                                                unsigned short* __restrict__ out, int n4) {
  int i = blockIdx.x * 256 + threadIdx.x;
  if (i >= n4) return;
  float4 v = reinterpret_cast<const float4*>(in)[i];
  unsigned int lo = (unsigned int)f2bf(v.x) | ((unsigned int)f2bf(v.y) << 16);
  unsigned int hi = (unsigned int)f2bf(v.z) | ((unsigned int)f2bf(v.w) << 16);
  reinterpret_cast<uint2*>(out)[i] = make_uint2(lo, hi);
}

// ---------------- QKV GEMM (128x128 tile, dbuf LDS) + bias + LN epilogue ----------------
// t==0 -> LN -> Qo[b,h,n,d]; t==1 -> LN -> Ko[b,h,n,d]; t==2 -> Vt[b,h,d,n] (transposed, packed)
__global__ __launch_bounds__(256) void qkv_gemm(
    const unsigned short* __restrict__ Xb, const unsigned short* __restrict__ Wb,
    const float* __restrict__ bias,
    const float* __restrict__ qg, const float* __restrict__ qbt,
    const float* __restrict__ kg, const float* __restrict__ kbt,
    unsigned short* __restrict__ Qo, unsigned short* __restrict__ Ko,
    unsigned short* __restrict__ Vt) {
  __shared__ unsigned short As[2][128 * 32];
  __shared__ unsigned short Bs[2][128 * 32];
  const int tid = threadIdx.x;
  const int wave = tid >> 6, lane = tid & 63;
  const int g = lane >> 4, cl = lane & 15;
  const int bm = blockIdx.x, bn = blockIdx.y;
  const int wr = (wave >> 1) * 64, wc = (wave & 1) * 64;

  f32x4 acc[4][4] = {};

  const int kc = (tid & 3) * 8;
  const unsigned short* ag0 = Xb + (size_t)(bm * 128 + (tid >> 2)) * CD + kc;
  const unsigned short* ag1 = ag0 + (size_t)64 * CD;
  const unsigned short* bg0 = Wb + (size_t)(bn * 128 + (tid >> 2)) * CD + kc;
  const unsigned short* bg1 = bg0 + (size_t)64 * CD;

#define QSTAGE(buf, k0)                             \
  do {                                              \
    gl2lds16(ag0 + (k0), &As[buf][tid * 8]);        \
    gl2lds16(ag1 + (k0), &As[buf][tid * 8 + 2048]); \
    gl2lds16(bg0 + (k0), &Bs[buf][tid * 8]);        \
    gl2lds16(bg1 + (k0), &Bs[buf][tid * 8 + 2048]); \
  } while (0)

  QSTAGE(0, 0);
  __syncthreads();
  const int NIT = CD / 32;  // 24
  for (int it = 0; it < NIT; ++it) {
    const int cur = it & 1;
    if (it + 1 < NIT) QSTAGE(cur ^ 1, (it + 1) * 32);
    bf16x8 af[4], bfr[4];
#pragma unroll
    for (int i = 0; i < 4; ++i) af[i] = *(const bf16x8*)&As[cur][(wr + i * 16 + cl) * 32 + g * 8];
#pragma unroll
    for (int j = 0; j < 4; ++j) bfr[j] = *(const bf16x8*)&Bs[cur][(wc + j * 16 + cl) * 32 + g * 8];
#pragma unroll
    for (int i = 0; i < 4; ++i)
#pragma unroll
      for (int j = 0; j < 4; ++j) acc[i][j] = MFMA(af[i], bfr[j], acc[i][j]);
    __syncthreads();
  }
#undef QSTAGE

  const int j0 = bn * 128 + wc;
  const int t = j0 / CD;
  const int h = (j0 % CD) / DH;
  float bia[4], gam[4] = {0, 0, 0, 0}, bet[4] = {0, 0, 0, 0};
#pragma unroll
  for (int j = 0; j < 4; ++j) {
    int d = j * 16 + cl;
    bia[j] = bias[j0 + d];
    if (t == 0) { gam[j] = qg[d] * QSC; bet[j] = qbt[d] * QSC; }  // fold softmax scale into Q
    else if (t == 1) { gam[j] = kg[d]; bet[j] = kbt[d]; }
  }

  if (t == 2) {
    // V transposed write: Vt[b][h][d][n], r=0..3 are 4 consecutive n -> one 8B store
#pragma unroll
    for (int i = 0; i < 4; ++i) {
      const int mrow = bm * 128 + wr + i * 16 + g * 4;
      const int b = mrow >> 11, nn = mrow & 2047;
#pragma unroll
      for (int j = 0; j < 4; ++j) {
        const int d = j * 16 + cl;
        unsigned int lo = (unsigned int)f2bf(acc[i][j][0] + bia[j]) |
                          ((unsigned int)f2bf(acc[i][j][1] + bia[j]) << 16);
        unsigned int hi2 = (unsigned int)f2bf(acc[i][j][2] + bia[j]) |
                           ((unsigned int)f2bf(acc[i][j][3] + bia[j]) << 16);
        *reinterpret_cast<uint2*>(&Vt[((size_t)(b * NH + h) * DH + d) * SEQ + nn]) =
            make_uint2(lo, hi2);
      }
    }
    return;
  }

  unsigned short* Out = (t == 0) ? Qo : Ko;
#pragma unroll
  for (int i = 0; i < 4; ++i) {
#pragma unroll
    for (int r = 0; r < 4; ++r) {
      float vj[4];
#pragma unroll
      for (int j = 0; j < 4; ++j) vj[j] = acc[i][j][r] + bia[j];
      const int m = bm * 128 + wr + i * 16 + g * 4 + r;
      const int b = m >> 11, n = m & 2047;
      size_t base = ((size_t)(b * NH + h) * SEQ + n) * DH;
      float s = vj[0] + vj[1] + vj[2] + vj[3];
      float ss = vj[0] * vj[0] + vj[1] * vj[1] + vj[2] * vj[2] + vj[3] * vj[3];
#pragma unroll
      for (int msk = 1; msk < 16; msk <<= 1) {
        s += __shfl_xor(s, msk, 64);
        ss += __shfl_xor(ss, msk, 64);
      }
      float mu = s * (1.0f / 64.0f);
      float var = ss * (1.0f / 64.0f) - mu * mu;
      float rstd = rsqrtf(var + 1e-5f);
#pragma unroll
      for (int j = 0; j < 4; ++j)
        Out[base + j * 16 + cl] = f2bf((vj[j] - mu) * rstd * gam[j] + bet[j]);
    }
  }
}

// ---------------- Flash attention: swapped QK^T, 32x32 MFMA, no-max softmax ----------------
// 4 waves x 32 q-rows, KVBLK=64. S^T = mfma(K, Q): lane holds S[key=crow(r,hi)+32ks][q=lane&31],
// crow(r,hi) = (r&3) + 8*(r>>2) + 4*hi. No max subtraction (scores bounded, see QSC note).
// Row-sum l via ones-MFMA into ol. XCD-aware block mapping: each XCD owns 6 contiguous heads.
__global__ __launch_bounds__(256, 3) void attn_fwd(
    const unsigned short* __restrict__ Qb, const unsigned short* __restrict__ Kb,
    const unsigned short* __restrict__ Vtb, unsigned short* __restrict__ Ob) {
  __shared__ unsigned short kl[2][64 * 64];   // [key][d], 128B rows, XOR-swizzled
  __shared__ unsigned short vt[2][64 * 64];   // [d][key], 128B rows, XOR-swizzled
  const int tid = threadIdx.x, wave = tid >> 6, lane = tid & 63;
  const int q32 = lane & 31, hi = lane >> 5;

  // XCD swizzle (T1): wg%8 = XCD; give each XCD a contiguous chunk of (bh, qb) space
  const int wg = blockIdx.x;
  const int lin = (wg & 7) * 96 + (wg >> 3);   // 768 = 8 * 96, bijective
  const int bh = lin >> 4;
  const int qbase = (lin & 15) * 128 + wave * 32;

  // Q fragments (B-operand: row=q=lane&31, k = dc*16 + hi*8 + i), pre-scaled by QSC*gamma
  const unsigned short* qrow = Qb + ((size_t)bh * SEQ + qbase + q32) * DH + hi * 8;
  bf16x8 qf[4];
#pragma unroll
  for (int dc = 0; dc < 4; ++dc) qf[dc] = *(const bf16x8*)&qrow[dc * 16];

  const unsigned short* Kh = Kb + (size_t)bh * SEQ * DH;
  const unsigned short* Vth = Vtb + (size_t)bh * DH * SEQ;

  const int sr = tid >> 3;
  const int sc = 8 * ((tid & 7) ^ (sr & 7));
  const int ksw = (q32 & 7) << 3;

  const short oneb = (short)0x3F80;  // bf16 1.0
  const bf16x8 onesv = {oneb, oneb, oneb, oneb, oneb, oneb, oneb, oneb};

#define ASTAGE(buf, kb0)                                                      \
  do {                                                                        \
    gl2lds16(&Kh[(size_t)((kb0) + sr) * DH + sc], &kl[buf][tid * 8]);         \
    gl2lds16(&Kh[(size_t)((kb0) + sr + 32) * DH + sc], &kl[buf][tid * 8 + 2048]); \
    gl2lds16(&Vth[(size_t)sr * SEQ + (kb0) + sc], &vt[buf][tid * 8]);         \
    gl2lds16(&Vth[(size_t)(sr + 32) * SEQ + (kb0) + sc], &vt[buf][tid * 8 + 2048]); \
  } while (0)

  f32x16 o0 = {}, o1 = {}, ol = {};

  ASTAGE(0, 0);
  __syncthreads();
  const int NT = SEQ / 64;  // 32
#pragma unroll 2
  for (int it = 0; it < NT; ++it) {
    const int cur = it & 1;
    if (it + 1 < NT) ASTAGE(cur ^ 1, (it + 1) * 64);

    // S^T = K . Q^T : A = K rows (key), B = Q rows (q)
    f32x16 s0 = {}, s1 = {};
    __builtin_amdgcn_s_setprio(1);
#pragma unroll
    for (int dc = 0; dc < 4; ++dc) {
      const int colb = dc * 16 + hi * 8;
      bf16x8 kf0 = *(const bf16x8*)&kl[cur][q32 * 64 + (colb ^ ksw)];
      bf16x8 kf1 = *(const bf16x8*)&kl[cur][(32 + q32) * 64 + (colb ^ ksw)];
      s0 = MFMA32(kf0, qf[dc], s0);
      s1 = MFMA32(kf1, qf[dc], s1);
    }
    __builtin_amdgcn_s_setprio(0);

    // P = exp2(S) directly: scores bounded (<= 11.5 in log2 domain), no max needed
#pragma unroll
    for (int r = 0; r < 16; ++r) {
      s0[r] = fexp2(s0[r]);
      s1[r] = fexp2(s1[r]);
    }

    // P -> bf16 A-frags in-register: pav[c][i] = P[q][key = c*16 + 8*hi + i]
    bf16x8 pav[4];
#pragma unroll
    for (int c = 0; c < 4; ++c) {
      const int b = 8 * (c & 1);
      unsigned int wA0, wA1, wB0, wB1;
      if (c < 2) {
        PACKBF(wA0, s0[b + 0], s0[b + 1]); PACKBF(wA1, s0[b + 2], s0[b + 3]);
        PACKBF(wB0, s0[b + 4], s0[b + 5]); PACKBF(wB1, s0[b + 6], s0[b + 7]);
      } else {
        PACKBF(wA0, s1[b + 0], s1[b + 1]); PACKBF(wA1, s1[b + 2], s1[b + 3]);
        PACKBF(wB0, s1[b + 4], s1[b + 5]); PACKBF(wB1, s1[b + 6], s1[b + 7]);
      }
      SWAP32(wA0, wB0);  // wA0 -> word0, wB0 -> word2
      SWAP32(wA1, wB1);  // wA1 -> word1, wB1 -> word3
      union { unsigned int w[4]; bf16x8 v; } u;
      u.w[0] = wA0; u.w[1] = wA1; u.w[2] = wB0; u.w[3] = wB1;
      pav[c] = u.v;
    }

    // PV: O[q][d] += P[q][key] . V^T[d][key]; row-sum l via ones-MFMA
    __builtin_amdgcn_s_setprio(1);
#pragma unroll
    for (int c = 0; c < 4; ++c) {
      const int colb = c * 16 + hi * 8;
      bf16x8 vf0 = *(const bf16x8*)&vt[cur][q32 * 64 + (colb ^ ksw)];
      bf16x8 vf1 = *(const bf16x8*)&vt[cur][(32 + q32) * 64 + (colb ^ ksw)];
      o0 = MFMA32(pav[c], vf0, o0);
      o1 = MFMA32(pav[c], vf1, o1);
      ol = MFMA32(pav[c], onesv, ol);
    }
    __builtin_amdgcn_s_setprio(0);
    __syncthreads();
  }
#undef ASTAGE

  const int b = bh / NH, h = bh % NH;
#pragma unroll
  for (int r = 0; r < 16; ++r) {
    const int qq = (r & 3) + 8 * (r >> 2) + 4 * hi;   // output row within 32
    const float iv = __builtin_amdgcn_rcpf(ol[r]);    // ol[r] = l for row qq
    size_t base = ((size_t)(b * SEQ + qbase + qq)) * CD + h * DH;
    Ob[base + q32] = f2bf(o0[r] * iv);
    Ob[base + 32 + q32] = f2bf(o1[r] * iv);
  }
}

// ---------------- Proj GEMM (128x128 tile, dbuf LDS) + bias, fp32 out ----------------
__global__ __launch_bounds__(256) void proj_gemm(
    const unsigned short* __restrict__ Ab, const unsigned short* __restrict__ Wb,
    const float* __restrict__ bias, float* __restrict__ out) {
  __shared__ unsigned short As[2][128 * 32];
  __shared__ unsigned short Bs[2][128 * 32];
  const int tid = threadIdx.x;
  const int wave = tid >> 6, lane = tid & 63;
  const int g = lane >> 4, cl = lane & 15;
  const int bm = blockIdx.x, bn = blockIdx.y;
  const int wr = (wave >> 1) * 64, wc = (wave & 1) * 64;

  f32x4 acc[4][4] = {};

  const int kc = (tid & 3) * 8;
  const unsigned short* ag0 = Ab + (size_t)(bm * 128 + (tid >> 2)) * CD + kc;
  const unsigned short* ag1 = ag0 + (size_t)64 * CD;
  const unsigned short* bg0 = Wb + (size_t)(bn * 128 + (tid >> 2)) * CD + kc;
  const unsigned short* bg1 = bg0 + (size_t)64 * CD;

#define PSTAGE(buf, k0)                             \
  do {                                              \
    gl2lds16(ag0 + (k0), &As[buf][tid * 8]);        \
    gl2lds16(ag1 + (k0), &As[buf][tid * 8 + 2048]); \
    gl2lds16(bg0 + (k0), &Bs[buf][tid * 8]);        \
    gl2lds16(bg1 + (k0), &Bs[buf][tid * 8 + 2048]); \
  } while (0)

  PSTAGE(0, 0);
  __syncthreads();
  const int NIT = CD / 32;  // 24
  for (int it = 0; it < NIT; ++it) {
    const int cur = it & 1;
    if (it + 1 < NIT) PSTAGE(cur ^ 1, (it + 1) * 32);
    bf16x8 af[4], bfr[4];
#pragma unroll
    for (int i = 0; i < 4; ++i) af[i] = *(const bf16x8*)&As[cur][(wr + i * 16 + cl) * 32 + g * 8];
#pragma unroll
    for (int j = 0; j < 4; ++j) bfr[j] = *(const bf16x8*)&Bs[cur][(wc + j * 16 + cl) * 32 + g * 8];
#pragma unroll
    for (int i = 0; i < 4; ++i)
#pragma unroll
      for (int j = 0; j < 4; ++j) acc[i][j] = MFMA(af[i], bfr[j], acc[i][j]);
    __syncthreads();
  }
#undef PSTAGE

  const int j0 = bn * 128 + wc;
  float pb4[4];
#pragma unroll
  for (int j = 0; j < 4; ++j) pb4[j] = bias[j0 + j * 16 + cl];
#pragma unroll
  for (int i = 0; i < 4; ++i) {
#pragma unroll
    for (int r = 0; r < 4; ++r) {
      const int m = bm * 128 + wr + i * 16 + g * 4 + r;
      float* orow = out + (size_t)m * CD + j0;
#pragma unroll
      for (int j = 0; j < 4; ++j) orow[j * 16 + cl] = acc[i][j][r] + pb4[j];
    }
  }
}

extern "C" void kernel_launch(void* const* d_in, const int* in_sizes, int n_in,
                              void* d_out, int out_size, void* d_ws, size_t ws_size,
                              hipStream_t stream) {
  const float* x = (const float*)d_in[0];
  const float* qkv_w = (const float*)d_in[1];
  const float* qkv_b = (const float*)d_in[2];
  const float* proj_w = (const float*)d_in[3];
  const float* proj_b = (const float*)d_in[4];
  const float* q_gamma = (const float*)d_in[5];
  const float* q_beta = (const float*)d_in[6];
  const float* k_gamma = (const float*)d_in[7];
  const float* k_beta = (const float*)d_in[8];
  float* out = (float*)d_out;

  char* w = (char*)d_ws;
  unsigned short* Xb = (unsigned short*)w; w += (size_t)MROWS * CD * 2;
  unsigned short* Wq = (unsigned short*)w; w += (size_t)NQKV * CD * 2;
  unsigned short* Wp = (unsigned short*)w; w += (size_t)CD * CD * 2;
  unsigned short* Qo = (unsigned short*)w; w += (size_t)BB * NH * SEQ * DH * 2;
  unsigned short* Ko = (unsigned short*)w; w += (size_t)BB * NH * SEQ * DH * 2;
  unsigned short* Vt = (unsigned short*)w; w += (size_t)BB * NH * SEQ * DH * 2;  // [b,h,d,n]
  unsigned short* Ob = (unsigned short*)w; w += (size_t)MROWS * CD * 2;

  cvt_bf16<<<MROWS * CD / 1024, 256, 0, stream>>>(x, Xb, MROWS * CD / 4);
  cvt_bf16<<<NQKV * CD / 1024, 256, 0, stream>>>(qkv_w, Wq, NQKV * CD / 4);
  cvt_bf16<<<CD * CD / 1024, 256, 0, stream>>>(proj_w, Wp, CD * CD / 4);

  qkv_gemm<<<dim3(MROWS / 128, NQKV / 128), 256, 0, stream>>>(
      Xb, Wq, qkv_b, q_gamma, q_beta, k_gamma, k_beta, Qo, Ko, Vt);

  attn_fwd<<<SEQ / 128 * BB * NH, 256, 0, stream>>>(Qo, Ko, Vt, Ob);

  proj_gemm<<<dim3(MROWS / 128, CD / 128), 256, 0, stream>>>(Ob, Wp, proj_b, out);
}

// Round 7
// 156.314 us; speedup vs baseline: 1.2033x; 1.0355x over previous
//
#include <hip/hip_runtime.h>
#include <hip/hip_bf16.h>
#include <cstdint>
#include <cstddef>

#define BB 4
#define SEQ 2048
#define CD 768
#define NH 12
#define DH 64
#define MROWS (BB*SEQ)      // 8192
#define NQKV (3*CD)         // 2304

typedef float f32x4 __attribute__((ext_vector_type(4)));
typedef float f32x16 __attribute__((ext_vector_type(16)));
typedef short bf16x8 __attribute__((ext_vector_type(8)));

static __device__ __forceinline__ unsigned short f2bf(float f) {
  union { float f; unsigned int u; } cv; cv.f = f;
  unsigned int u = cv.u;
  unsigned int r = (u + 0x7FFFu + ((u >> 16) & 1u)) >> 16;
  return (unsigned short)r;
}

// raw v_exp_f32: our exponents are bounded (|x| <= ~23), no OCML fixups needed
static __device__ __forceinline__ float fexp2(float x) {
#if __has_builtin(__builtin_amdgcn_exp2f)
  return __builtin_amdgcn_exp2f(x);
#else
  float r; asm("v_exp_f32 %0, %1" : "=v"(r) : "v"(x)); return r;
#endif
}

#define GAS __attribute__((address_space(1)))
#define LAS __attribute__((address_space(3)))
static __device__ __forceinline__ void gl2lds16(const void* g, void* l) {
  __builtin_amdgcn_global_load_lds((const GAS void*)g, (LAS void*)l, 16, 0, 0);
}

#define MFMA(a, b, c) __builtin_amdgcn_mfma_f32_16x16x32_bf16((a), (b), (c), 0, 0, 0)
#define MFMA32(a, b, c) __builtin_amdgcn_mfma_f32_32x32x16_bf16((a), (b), (c), 0, 0, 0)
#define PACKBF(dst, x, y) asm("v_cvt_pk_bf16_f32 %0, %1, %2" : "=v"(dst) : "v"(x), "v"(y))
#define SWAP32(a, b) asm("v_permlane32_swap_b32 %0, %1" : "+v"(a), "+v"(b))

// 0.125 (1/sqrt(Dh)) * log2(e): folded into Q's gamma/beta so softmax uses exp2 directly.
#define QSC 0.18033688011112042f

// ---------------- fp32 -> bf16 convert ----------------
__global__ __launch_bounds__(256) void cvt_bf16(const float* __restrict__ in,
                                                unsigned short* __restrict__ out, int n4) {
  int i = blockIdx.x * 256 + threadIdx.x;
  if (i >= n4) return;
  float4 v = reinterpret_cast<const float4*>(in)[i];
  unsigned int lo = (unsigned int)f2bf(v.x) | ((unsigned int)f2bf(v.y) << 16);
  unsigned int hi = (unsigned int)f2bf(v.z) | ((unsigned int)f2bf(v.w) << 16);
  reinterpret_cast<uint2*>(out)[i] = make_uint2(lo, hi);
}

// ---------------- QKV GEMM: 256x256 tile, BK=64, 8 waves, swizzled LDS ----------------
// LDS rows are 64 bf16 = 128B; XOR-swizzle (row&7)<<3 both sides -> conflict-free ds_read_b128.
// t==0 -> LN -> Qo[b,h,n,d]; t==1 -> LN -> Ko[b,h,n,d]; t==2 -> Vt[b,h,d,n] (transposed)
__global__ __launch_bounds__(512, 2) void qkv_gemm(
    const unsigned short* __restrict__ Xb, const unsigned short* __restrict__ Wb,
    const float* __restrict__ bias,
    const float* __restrict__ qg, const float* __restrict__ qbt,
    const float* __restrict__ kg, const float* __restrict__ kbt,
    unsigned short* __restrict__ Qo, unsigned short* __restrict__ Ko,
    unsigned short* __restrict__ Vt) {
  __shared__ unsigned short Als[2][256 * 64];   // 64KB
  __shared__ unsigned short Bls[2][256 * 64];   // 64KB
  const int tid = threadIdx.x;
  const int wid = tid >> 6, lane = tid & 63;
  const int g = lane >> 4, cl = lane & 15;
  const int wm = wid >> 2, wn = wid & 3;        // 2M x 4N wave grid

  // XCD-bijective swizzle: grid 288 = 8 * 36
  const int wg = blockIdx.x;
  const int wgid = (wg & 7) * 36 + (wg >> 3);
  const int bm = wgid / 9, bn = wgid % 9;

  f32x4 acc[8][4] = {};

  // staging: thread loads 16B; dest linear (p*4096 + tid*8), source col pre-swizzled
  const int srow = tid >> 3;                    // 0..63
  const int scol = ((tid & 7) ^ (srow & 7)) * 8;  // (p*64)&7==0 so same for all p
  const unsigned short* Abase = Xb + (size_t)(bm * 256 + srow) * CD + scol;
  const unsigned short* Bbase = Wb + (size_t)(bn * 256 + srow) * CD + scol;

#define STG(buf, kt)                                                          \
  do {                                                                        \
    gl2lds16(Abase + (size_t)0 * 64 * CD + (kt) * 64, &Als[buf][0 * 4096 + tid * 8]); \
    gl2lds16(Abase + (size_t)1 * 64 * CD + (kt) * 64, &Als[buf][1 * 4096 + tid * 8]); \
    gl2lds16(Abase + (size_t)2 * 64 * CD + (kt) * 64, &Als[buf][2 * 4096 + tid * 8]); \
    gl2lds16(Abase + (size_t)3 * 64 * CD + (kt) * 64, &Als[buf][3 * 4096 + tid * 8]); \
    gl2lds16(Bbase + (size_t)0 * 64 * CD + (kt) * 64, &Bls[buf][0 * 4096 + tid * 8]); \
    gl2lds16(Bbase + (size_t)1 * 64 * CD + (kt) * 64, &Bls[buf][1 * 4096 + tid * 8]); \
    gl2lds16(Bbase + (size_t)2 * 64 * CD + (kt) * 64, &Bls[buf][2 * 4096 + tid * 8]); \
    gl2lds16(Bbase + (size_t)3 * 64 * CD + (kt) * 64, &Bls[buf][3 * 4096 + tid * 8]); \
  } while (0)

  STG(0, 0);
  __syncthreads();
  const int NKT = CD / 64;  // 12
  for (int kt = 0; kt < NKT; ++kt) {
    const int cur = kt & 1;
    if (kt + 1 < NKT) STG(cur ^ 1, kt + 1);
    bf16x8 bfr[4][2];
#pragma unroll
    for (int j = 0; j < 4; ++j) {
      const int Bcol = wn * 64 + j * 16 + cl;
      const int sw = (Bcol & 7) << 3;
      bfr[j][0] = *(const bf16x8*)&Bls[cur][Bcol * 64 + ((g * 8) ^ sw)];
      bfr[j][1] = *(const bf16x8*)&Bls[cur][Bcol * 64 + ((32 + g * 8) ^ sw)];
    }
    __builtin_amdgcn_s_setprio(1);
#pragma unroll
    for (int i = 0; i < 8; ++i) {
      const int Arow = wm * 128 + i * 16 + cl;
      const int sw = (Arow & 7) << 3;
      bf16x8 a0 = *(const bf16x8*)&Als[cur][Arow * 64 + ((g * 8) ^ sw)];
      bf16x8 a1 = *(const bf16x8*)&Als[cur][Arow * 64 + ((32 + g * 8) ^ sw)];
#pragma unroll
      for (int j = 0; j < 4; ++j) {
        acc[i][j] = MFMA(a0, bfr[j][0], acc[i][j]);
        acc[i][j] = MFMA(a1, bfr[j][1], acc[i][j]);
      }
    }
    __builtin_amdgcn_s_setprio(0);
    __syncthreads();
  }
#undef STG

  // epilogue: wave's 64 cols = one (t, h) block exactly
  const int j0 = bn * 256 + wn * 64;
  const int t = j0 / CD;
  const int h = (j0 % CD) / DH;
  float bia[4], gam[4] = {0, 0, 0, 0}, bet[4] = {0, 0, 0, 0};
#pragma unroll
  for (int j = 0; j < 4; ++j) {
    int d = j * 16 + cl;
    bia[j] = bias[j0 + d];
    if (t == 0) { gam[j] = qg[d] * QSC; bet[j] = qbt[d] * QSC; }
    else if (t == 1) { gam[j] = kg[d]; bet[j] = kbt[d]; }
  }

  if (t == 2) {
    // V transposed write: Vt[b][h][d][n], r=0..3 are 4 consecutive n -> one 8B store
#pragma unroll
    for (int i = 0; i < 8; ++i) {
      const int mrow = bm * 256 + wm * 128 + i * 16 + g * 4;
      const int b = mrow >> 11, nn = mrow & 2047;
#pragma unroll
      for (int j = 0; j < 4; ++j) {
        const int d = j * 16 + cl;
        unsigned int lo = (unsigned int)f2bf(acc[i][j][0] + bia[j]) |
                          ((unsigned int)f2bf(acc[i][j][1] + bia[j]) << 16);
        unsigned int hi2 = (unsigned int)f2bf(acc[i][j][2] + bia[j]) |
                           ((unsigned int)f2bf(acc[i][j][3] + bia[j]) << 16);
        *reinterpret_cast<uint2*>(&Vt[((size_t)(b * NH + h) * DH + d) * SEQ + nn]) =
            make_uint2(lo, hi2);
      }
    }
    return;
  }

  unsigned short* Out = (t == 0) ? Qo : Ko;
#pragma unroll
  for (int i = 0; i < 8; ++i) {
#pragma unroll
    for (int r = 0; r < 4; ++r) {
      float vj[4];
#pragma unroll
      for (int j = 0; j < 4; ++j) vj[j] = acc[i][j][r] + bia[j];
      const int m = bm * 256 + wm * 128 + i * 16 + g * 4 + r;
      const int b = m >> 11, n = m & 2047;
      size_t base = ((size_t)(b * NH + h) * SEQ + n) * DH;
      float s = vj[0] + vj[1] + vj[2] + vj[3];
      float ss = vj[0] * vj[0] + vj[1] * vj[1] + vj[2] * vj[2] + vj[3] * vj[3];
#pragma unroll
      for (int msk = 1; msk < 16; msk <<= 1) {
        s += __shfl_xor(s, msk, 64);
        ss += __shfl_xor(ss, msk, 64);
      }
      float mu = s * (1.0f / 64.0f);
      float var = ss * (1.0f / 64.0f) - mu * mu;
      float rstd = rsqrtf(var + 1e-5f);
#pragma unroll
      for (int j = 0; j < 4; ++j)
        Out[base + j * 16 + cl] = f2bf((vj[j] - mu) * rstd * gam[j] + bet[j]);
    }
  }
}

// ---------------- Flash attention: swapped QK^T, 32x32 MFMA, no-max softmax ----------------
__global__ __launch_bounds__(256, 3) void attn_fwd(
    const unsigned short* __restrict__ Qb, const unsigned short* __restrict__ Kb,
    const unsigned short* __restrict__ Vtb, unsigned short* __restrict__ Ob) {
  __shared__ unsigned short kl[2][64 * 64];   // [key][d], 128B rows, XOR-swizzled
  __shared__ unsigned short vt[2][64 * 64];   // [d][key], 128B rows, XOR-swizzled
  const int tid = threadIdx.x, wave = tid >> 6, lane = tid & 63;
  const int q32 = lane & 31, hi = lane >> 5;

  // XCD swizzle (T1): wg%8 = XCD; each XCD owns a contiguous chunk of (bh, qb) space
  const int wg = blockIdx.x;
  const int lin = (wg & 7) * 96 + (wg >> 3);   // 768 = 8 * 96, bijective
  const int bh = lin >> 4;
  const int qbase = (lin & 15) * 128 + wave * 32;

  const unsigned short* qrow = Qb + ((size_t)bh * SEQ + qbase + q32) * DH + hi * 8;
  bf16x8 qf[4];
#pragma unroll
  for (int dc = 0; dc < 4; ++dc) qf[dc] = *(const bf16x8*)&qrow[dc * 16];

  const unsigned short* Kh = Kb + (size_t)bh * SEQ * DH;
  const unsigned short* Vth = Vtb + (size_t)bh * DH * SEQ;

  const int sr = tid >> 3;
  const int sc = 8 * ((tid & 7) ^ (sr & 7));
  const int ksw = (q32 & 7) << 3;

  const short oneb = (short)0x3F80;  // bf16 1.0
  const bf16x8 onesv = {oneb, oneb, oneb, oneb, oneb, oneb, oneb, oneb};

#define ASTAGE(buf, kb0)                                                      \
  do {                                                                        \
    gl2lds16(&Kh[(size_t)((kb0) + sr) * DH + sc], &kl[buf][tid * 8]);         \
    gl2lds16(&Kh[(size_t)((kb0) + sr + 32) * DH + sc], &kl[buf][tid * 8 + 2048]); \
    gl2lds16(&Vth[(size_t)sr * SEQ + (kb0) + sc], &vt[buf][tid * 8]);         \
    gl2lds16(&Vth[(size_t)(sr + 32) * SEQ + (kb0) + sc], &vt[buf][tid * 8 + 2048]); \
  } while (0)

  f32x16 o0 = {}, o1 = {}, ol = {};

  ASTAGE(0, 0);
  __syncthreads();
  const int NT = SEQ / 64;  // 32
#pragma unroll 2
  for (int it = 0; it < NT; ++it) {
    const int cur = it & 1;
    if (it + 1 < NT) ASTAGE(cur ^ 1, (it + 1) * 64);

    f32x16 s0 = {}, s1 = {};
    __builtin_amdgcn_s_setprio(1);
#pragma unroll
    for (int dc = 0; dc < 4; ++dc) {
      const int colb = dc * 16 + hi * 8;
      bf16x8 kf0 = *(const bf16x8*)&kl[cur][q32 * 64 + (colb ^ ksw)];
      bf16x8 kf1 = *(const bf16x8*)&kl[cur][(32 + q32) * 64 + (colb ^ ksw)];
      s0 = MFMA32(kf0, qf[dc], s0);
      s1 = MFMA32(kf1, qf[dc], s1);
    }
    __builtin_amdgcn_s_setprio(0);

#pragma unroll
    for (int r = 0; r < 16; ++r) {
      s0[r] = fexp2(s0[r]);
      s1[r] = fexp2(s1[r]);
    }

    bf16x8 pav[4];
#pragma unroll
    for (int c = 0; c < 4; ++c) {
      const int b = 8 * (c & 1);
      unsigned int wA0, wA1, wB0, wB1;
      if (c < 2) {
        PACKBF(wA0, s0[b + 0], s0[b + 1]); PACKBF(wA1, s0[b + 2], s0[b + 3]);
        PACKBF(wB0, s0[b + 4], s0[b + 5]); PACKBF(wB1, s0[b + 6], s0[b + 7]);
      } else {
        PACKBF(wA0, s1[b + 0], s1[b + 1]); PACKBF(wA1, s1[b + 2], s1[b + 3]);
        PACKBF(wB0, s1[b + 4], s1[b + 5]); PACKBF(wB1, s1[b + 6], s1[b + 7]);
      }
      SWAP32(wA0, wB0);
      SWAP32(wA1, wB1);
      union { unsigned int w[4]; bf16x8 v; } u;
      u.w[0] = wA0; u.w[1] = wA1; u.w[2] = wB0; u.w[3] = wB1;
      pav[c] = u.v;
    }

    __builtin_amdgcn_s_setprio(1);
#pragma unroll
    for (int c = 0; c < 4; ++c) {
      const int colb = c * 16 + hi * 8;
      bf16x8 vf0 = *(const bf16x8*)&vt[cur][q32 * 64 + (colb ^ ksw)];
      bf16x8 vf1 = *(const bf16x8*)&vt[cur][(32 + q32) * 64 + (colb ^ ksw)];
      o0 = MFMA32(pav[c], vf0, o0);
      o1 = MFMA32(pav[c], vf1, o1);
      ol = MFMA32(pav[c], onesv, ol);
    }
    __builtin_amdgcn_s_setprio(0);
    __syncthreads();
  }
#undef ASTAGE

  const int b = bh / NH, h = bh % NH;
#pragma unroll
  for (int r = 0; r < 16; ++r) {
    const int qq = (r & 3) + 8 * (r >> 2) + 4 * hi;
    const float iv = __builtin_amdgcn_rcpf(ol[r]);
    size_t base = ((size_t)(b * SEQ + qbase + qq)) * CD + h * DH;
    Ob[base + q32] = f2bf(o0[r] * iv);
    Ob[base + 32 + q32] = f2bf(o1[r] * iv);
  }
}

// ---------------- Proj GEMM: 128x128 tile, BK=64, swizzled LDS, fp32 out ----------------
__global__ __launch_bounds__(256) void proj_gemm(
    const unsigned short* __restrict__ Ab, const unsigned short* __restrict__ Wb,
    const float* __restrict__ bias, float* __restrict__ out) {
  __shared__ unsigned short Als[2][128 * 64];   // 32KB
  __shared__ unsigned short Bls[2][128 * 64];   // 32KB
  const int tid = threadIdx.x;
  const int wid = tid >> 6, lane = tid & 63;
  const int g = lane >> 4, cl = lane & 15;
  const int bm = blockIdx.x, bn = blockIdx.y;
  const int wr = (wid >> 1) * 64, wc = (wid & 1) * 64;

  f32x4 acc[4][4] = {};

  const int srow = tid >> 3;                      // 0..31
  const int scol = ((tid & 7) ^ (srow & 7)) * 8;  // (p*32)&7==0
  const unsigned short* Abase = Ab + (size_t)(bm * 128 + srow) * CD + scol;
  const unsigned short* Bbase = Wb + (size_t)(bn * 128 + srow) * CD + scol;

#define PSTG(buf, kt)                                                         \
  do {                                                                        \
    gl2lds16(Abase + (size_t)0 * 32 * CD + (kt) * 64, &Als[buf][0 * 2048 + tid * 8]); \
    gl2lds16(Abase + (size_t)1 * 32 * CD + (kt) * 64, &Als[buf][1 * 2048 + tid * 8]); \
    gl2lds16(Abase + (size_t)2 * 32 * CD + (kt) * 64, &Als[buf][2 * 2048 + tid * 8]); \
    gl2lds16(Abase + (size_t)3 * 32 * CD + (kt) * 64, &Als[buf][3 * 2048 + tid * 8]); \
    gl2lds16(Bbase + (size_t)0 * 32 * CD + (kt) * 64, &Bls[buf][0 * 2048 + tid * 8]); \
    gl2lds16(Bbase + (size_t)1 * 32 * CD + (kt) * 64, &Bls[buf][1 * 2048 + tid * 8]); \
    gl2lds16(Bbase + (size_t)2 * 32 * CD + (kt) * 64, &Bls[buf][2 * 2048 + tid * 8]); \
    gl2lds16(Bbase + (size_t)3 * 32 * CD + (kt) * 64, &Bls[buf][3 * 2048 + tid * 8]); \
  } while (0)

  PSTG(0, 0);
  __syncthreads();
  const int NKT = CD / 64;  // 12
  for (int kt = 0; kt < NKT; ++kt) {
    const int cur = kt & 1;
    if (kt + 1 < NKT) PSTG(cur ^ 1, kt + 1);
    bf16x8 bfr[4][2];
#pragma unroll
    for (int j = 0; j < 4; ++j) {
      const int Bcol = wc + j * 16 + cl;
      const int sw = (Bcol & 7) << 3;
      bfr[j][0] = *(const bf16x8*)&Bls[cur][Bcol * 64 + ((g * 8) ^ sw)];
      bfr[j][1] = *(const bf16x8*)&Bls[cur][Bcol * 64 + ((32 + g * 8) ^ sw)];
    }
    __builtin_amdgcn_s_setprio(1);
#pragma unroll
    for (int i = 0; i < 4; ++i) {
      const int Arow = wr + i * 16 + cl;
      const int sw = (Arow & 7) << 3;
      bf16x8 a0 = *(const bf16x8*)&Als[cur][Arow * 64 + ((g * 8) ^ sw)];
      bf16x8 a1 = *(const bf16x8*)&Als[cur][Arow * 64 + ((32 + g * 8) ^ sw)];
#pragma unroll
      for (int j = 0; j < 4; ++j) {
        acc[i][j] = MFMA(a0, bfr[j][0], acc[i][j]);
        acc[i][j] = MFMA(a1, bfr[j][1], acc[i][j]);
      }
    }
    __builtin_amdgcn_s_setprio(0);
    __syncthreads();
  }
#undef PSTG

  const int j0 = bn * 128 + wc;
  float pb4[4];
#pragma unroll
  for (int j = 0; j < 4; ++j) pb4[j] = bias[j0 + j * 16 + cl];
#pragma unroll
  for (int i = 0; i < 4; ++i) {
#pragma unroll
    for (int r = 0; r < 4; ++r) {
      const int m = bm * 128 + wr + i * 16 + g * 4 + r;
      float* orow = out + (size_t)m * CD + j0;
#pragma unroll
      for (int j = 0; j < 4; ++j) orow[j * 16 + cl] = acc[i][j][r] + pb4[j];
    }
  }
}

extern "C" void kernel_launch(void* const* d_in, const int* in_sizes, int n_in,
                              void* d_out, int out_size, void* d_ws, size_t ws_size,
                              hipStream_t stream) {
  const float* x = (const float*)d_in[0];
  const float* qkv_w = (const float*)d_in[1];
  const float* qkv_b = (const float*)d_in[2];
  const float* proj_w = (const float*)d_in[3];
  const float* proj_b = (const float*)d_in[4];
  const float* q_gamma = (const float*)d_in[5];
  const float* q_beta = (const float*)d_in[6];
  const float* k_gamma = (const float*)d_in[7];
  const float* k_beta = (const float*)d_in[8];
  float* out = (float*)d_out;

  char* w = (char*)d_ws;
  unsigned short* Xb = (unsigned short*)w; w += (size_t)MROWS * CD * 2;
  unsigned short* Wq = (unsigned short*)w; w += (size_t)NQKV * CD * 2;
  unsigned short* Wp = (unsigned short*)w; w += (size_t)CD * CD * 2;
  unsigned short* Qo = (unsigned short*)w; w += (size_t)BB * NH * SEQ * DH * 2;
  unsigned short* Ko = (unsigned short*)w; w += (size_t)BB * NH * SEQ * DH * 2;
  unsigned short* Vt = (unsigned short*)w; w += (size_t)BB * NH * SEQ * DH * 2;  // [b,h,d,n]
  unsigned short* Ob = (unsigned short*)w; w += (size_t)MROWS * CD * 2;

  cvt_bf16<<<MROWS * CD / 1024, 256, 0, stream>>>(x, Xb, MROWS * CD / 4);
  cvt_bf16<<<NQKV * CD / 1024, 256, 0, stream>>>(qkv_w, Wq, NQKV * CD / 4);
  cvt_bf16<<<CD * CD / 1024, 256, 0, stream>>>(proj_w, Wp, CD * CD / 4);

  qkv_gemm<<<(MROWS / 256) * (NQKV / 256), 512, 0, stream>>>(
      Xb, Wq, qkv_b, q_gamma, q_beta, k_gamma, k_beta, Qo, Ko, Vt);

  attn_fwd<<<SEQ / 128 * BB * NH, 256, 0, stream>>>(Qo, Ko, Vt, Ob);

  proj_gemm<<<dim3(MROWS / 128, CD / 128), 256, 0, stream>>>(Ob, Wp, proj_b, out);
}

// Round 8
// 147.804 us; speedup vs baseline: 1.2726x; 1.0576x over previous
//
#include <hip/hip_runtime.h>
#include <hip/hip_bf16.h>
#include <cstdint>
#include <cstddef>

#define BB 4
#define SEQ 2048
#define CD 768
#define NH 12
#define DH 64
#define MROWS (BB*SEQ)      // 8192
#define NQKV (3*CD)         // 2304

typedef float f32x4 __attribute__((ext_vector_type(4)));
typedef float f32x16 __attribute__((ext_vector_type(16)));
typedef short bf16x8 __attribute__((ext_vector_type(8)));

static __device__ __forceinline__ unsigned short f2bf(float f) {
  union { float f; unsigned int u; } cv; cv.f = f;
  unsigned int u = cv.u;
  unsigned int r = (u + 0x7FFFu + ((u >> 16) & 1u)) >> 16;
  return (unsigned short)r;
}

// raw v_exp_f32: our exponents are bounded (|x| <= ~23), no OCML fixups needed
static __device__ __forceinline__ float fexp2(float x) {
#if __has_builtin(__builtin_amdgcn_exp2f)
  return __builtin_amdgcn_exp2f(x);
#else
  float r; asm("v_exp_f32 %0, %1" : "=v"(r) : "v"(x)); return r;
#endif
}

#define GAS __attribute__((address_space(1)))
#define LAS __attribute__((address_space(3)))
static __device__ __forceinline__ void gl2lds16(const void* g, void* l) {
  __builtin_amdgcn_global_load_lds((const GAS void*)g, (LAS void*)l, 16, 0, 0);
}

#define MFMA(a, b, c) __builtin_amdgcn_mfma_f32_16x16x32_bf16((a), (b), (c), 0, 0, 0)
#define MFMA32(a, b, c) __builtin_amdgcn_mfma_f32_32x32x16_bf16((a), (b), (c), 0, 0, 0)
#define PACKBF(dst, x, y) asm("v_cvt_pk_bf16_f32 %0, %1, %2" : "=v"(dst) : "v"(x), "v"(y))
#define SWAP32(a, b) asm("v_permlane32_swap_b32 %0, %1" : "+v"(a), "+v"(b))

// 0.125 (1/sqrt(Dh)) * log2(e): folded into Q's gamma/beta so softmax uses exp2 directly.
#define QSC 0.18033688011112042f

// ---------------- fp32 -> bf16 convert ----------------
__global__ __launch_bounds__(256) void cvt_bf16(const float* __restrict__ in,
                                                unsigned short* __restrict__ out, int n4) {
  int i = blockIdx.x * 256 + threadIdx.x;
  if (i >= n4) return;
  float4 v = reinterpret_cast<const float4*>(in)[i];
  unsigned int lo = (unsigned int)f2bf(v.x) | ((unsigned int)f2bf(v.y) << 16);
  unsigned int hi = (unsigned int)f2bf(v.z) | ((unsigned int)f2bf(v.w) << 16);
  reinterpret_cast<uint2*>(out)[i] = make_uint2(lo, hi);
}

// ---------------- QKV GEMM: 128x128 tile, BK=64, 4 waves, swizzled LDS, 2 blocks/CU ----------------
// LDS rows 64 bf16 = 128B; XOR-swizzle (row&7)<<3 both sides -> conflict-free ds_read_b128.
// t==0 -> LN -> Qo[b,h,n,d]; t==1 -> LN -> Ko[b,h,n,d]; t==2 -> Vt[b,h,d,n] (transposed)
__global__ __launch_bounds__(256) void qkv_gemm(
    const unsigned short* __restrict__ Xb, const unsigned short* __restrict__ Wb,
    const float* __restrict__ bias,
    const float* __restrict__ qg, const float* __restrict__ qbt,
    const float* __restrict__ kg, const float* __restrict__ kbt,
    unsigned short* __restrict__ Qo, unsigned short* __restrict__ Ko,
    unsigned short* __restrict__ Vt) {
  __shared__ unsigned short Als[2][128 * 64];   // 32KB
  __shared__ unsigned short Bls[2][128 * 64];   // 32KB
  const int tid = threadIdx.x;
  const int wid = tid >> 6, lane = tid & 63;
  const int g = lane >> 4, cl = lane & 15;
  const int wr = (wid >> 1) * 64, wc = (wid & 1) * 64;

  // XCD-bijective swizzle: grid 1152 = 8 * 144; contiguous wgid share bm (A-panel L2 reuse)
  const int wg = blockIdx.x;
  const int wgid = (wg & 7) * 144 + (wg >> 3);
  const int bm = wgid / 18, bn = wgid % 18;

  f32x4 acc[4][4] = {};

  const int srow = tid >> 3;                      // 0..31
  const int scol = ((tid & 7) ^ (srow & 7)) * 8;  // pre-swizzled source col
  const unsigned short* Abase = Xb + (size_t)(bm * 128 + srow) * CD + scol;
  const unsigned short* Bbase = Wb + (size_t)(bn * 128 + srow) * CD + scol;

#define QSTG(buf, kt)                                                         \
  do {                                                                        \
    gl2lds16(Abase + (size_t)0 * 32 * CD + (kt) * 64, &Als[buf][0 * 2048 + tid * 8]); \
    gl2lds16(Abase + (size_t)1 * 32 * CD + (kt) * 64, &Als[buf][1 * 2048 + tid * 8]); \
    gl2lds16(Abase + (size_t)2 * 32 * CD + (kt) * 64, &Als[buf][2 * 2048 + tid * 8]); \
    gl2lds16(Abase + (size_t)3 * 32 * CD + (kt) * 64, &Als[buf][3 * 2048 + tid * 8]); \
    gl2lds16(Bbase + (size_t)0 * 32 * CD + (kt) * 64, &Bls[buf][0 * 2048 + tid * 8]); \
    gl2lds16(Bbase + (size_t)1 * 32 * CD + (kt) * 64, &Bls[buf][1 * 2048 + tid * 8]); \
    gl2lds16(Bbase + (size_t)2 * 32 * CD + (kt) * 64, &Bls[buf][2 * 2048 + tid * 8]); \
    gl2lds16(Bbase + (size_t)3 * 32 * CD + (kt) * 64, &Bls[buf][3 * 2048 + tid * 8]); \
  } while (0)

  QSTG(0, 0);
  __syncthreads();
  const int NKT = CD / 64;  // 12
  for (int kt = 0; kt < NKT; ++kt) {
    const int cur = kt & 1;
    if (kt + 1 < NKT) QSTG(cur ^ 1, kt + 1);
    bf16x8 bfr[4][2];
#pragma unroll
    for (int j = 0; j < 4; ++j) {
      const int Bcol = wc + j * 16 + cl;
      const int sw = (Bcol & 7) << 3;
      bfr[j][0] = *(const bf16x8*)&Bls[cur][Bcol * 64 + ((g * 8) ^ sw)];
      bfr[j][1] = *(const bf16x8*)&Bls[cur][Bcol * 64 + ((32 + g * 8) ^ sw)];
    }
    __builtin_amdgcn_s_setprio(1);
#pragma unroll
    for (int i = 0; i < 4; ++i) {
      const int Arow = wr + i * 16 + cl;
      const int sw = (Arow & 7) << 3;
      bf16x8 a0 = *(const bf16x8*)&Als[cur][Arow * 64 + ((g * 8) ^ sw)];
      bf16x8 a1 = *(const bf16x8*)&Als[cur][Arow * 64 + ((32 + g * 8) ^ sw)];
#pragma unroll
      for (int j = 0; j < 4; ++j) {
        acc[i][j] = MFMA(a0, bfr[j][0], acc[i][j]);
        acc[i][j] = MFMA(a1, bfr[j][1], acc[i][j]);
      }
    }
    __builtin_amdgcn_s_setprio(0);
    __syncthreads();
  }
#undef QSTG

  // epilogue: wave's 64 cols = one (t, h) block exactly
  const int j0 = bn * 128 + wc;
  const int t = j0 / CD;
  const int h = (j0 % CD) / DH;
  float bia[4], gam[4] = {0, 0, 0, 0}, bet[4] = {0, 0, 0, 0};
#pragma unroll
  for (int j = 0; j < 4; ++j) {
    int d = j * 16 + cl;
    bia[j] = bias[j0 + d];
    if (t == 0) { gam[j] = qg[d] * QSC; bet[j] = qbt[d] * QSC; }
    else if (t == 1) { gam[j] = kg[d]; bet[j] = kbt[d]; }
  }

  if (t == 2) {
    // V transposed write: Vt[b][h][d][n], r=0..3 are 4 consecutive n -> one 8B store
#pragma unroll
    for (int i = 0; i < 4; ++i) {
      const int mrow = bm * 128 + wr + i * 16 + g * 4;
      const int b = mrow >> 11, nn = mrow & 2047;
#pragma unroll
      for (int j = 0; j < 4; ++j) {
        const int d = j * 16 + cl;
        unsigned int lo = (unsigned int)f2bf(acc[i][j][0] + bia[j]) |
                          ((unsigned int)f2bf(acc[i][j][1] + bia[j]) << 16);
        unsigned int hi2 = (unsigned int)f2bf(acc[i][j][2] + bia[j]) |
                           ((unsigned int)f2bf(acc[i][j][3] + bia[j]) << 16);
        *reinterpret_cast<uint2*>(&Vt[((size_t)(b * NH + h) * DH + d) * SEQ + nn]) =
            make_uint2(lo, hi2);
      }
    }
    return;
  }

  unsigned short* Out = (t == 0) ? Qo : Ko;
#pragma unroll
  for (int i = 0; i < 4; ++i) {
#pragma unroll
    for (int r = 0; r < 4; ++r) {
      float vj[4];
#pragma unroll
      for (int j = 0; j < 4; ++j) vj[j] = acc[i][j][r] + bia[j];
      const int m = bm * 128 + wr + i * 16 + g * 4 + r;
      const int b = m >> 11, n = m & 2047;
      size_t base = ((size_t)(b * NH + h) * SEQ + n) * DH;
      float s = vj[0] + vj[1] + vj[2] + vj[3];
      float ss = vj[0] * vj[0] + vj[1] * vj[1] + vj[2] * vj[2] + vj[3] * vj[3];
#pragma unroll
      for (int msk = 1; msk < 16; msk <<= 1) {
        s += __shfl_xor(s, msk, 64);
        ss += __shfl_xor(ss, msk, 64);
      }
      float mu = s * (1.0f / 64.0f);
      float var = ss * (1.0f / 64.0f) - mu * mu;
      float rstd = rsqrtf(var + 1e-5f);
#pragma unroll
      for (int j = 0; j < 4; ++j)
        Out[base + j * 16 + cl] = f2bf((vj[j] - mu) * rstd * gam[j] + bet[j]);
    }
  }
}

// ---------------- Flash attention: swapped QK^T, 32x32 MFMA, no-max softmax ----------------
__global__ __launch_bounds__(256, 3) void attn_fwd(
    const unsigned short* __restrict__ Qb, const unsigned short* __restrict__ Kb,
    const unsigned short* __restrict__ Vtb, unsigned short* __restrict__ Ob) {
  __shared__ unsigned short kl[2][64 * 64];   // [key][d], 128B rows, XOR-swizzled
  __shared__ unsigned short vt[2][64 * 64];   // [d][key], 128B rows, XOR-swizzled
  const int tid = threadIdx.x, wave = tid >> 6, lane = tid & 63;
  const int q32 = lane & 31, hi = lane >> 5;

  // XCD swizzle (T1): wg%8 = XCD; each XCD owns a contiguous chunk of (bh, qb) space
  const int wg = blockIdx.x;
  const int lin = (wg & 7) * 96 + (wg >> 3);   // 768 = 8 * 96, bijective
  const int bh = lin >> 4;
  const int qbase = (lin & 15) * 128 + wave * 32;

  const unsigned short* qrow = Qb + ((size_t)bh * SEQ + qbase + q32) * DH + hi * 8;
  bf16x8 qf[4];
#pragma unroll
  for (int dc = 0; dc < 4; ++dc) qf[dc] = *(const bf16x8*)&qrow[dc * 16];

  const unsigned short* Kh = Kb + (size_t)bh * SEQ * DH;
  const unsigned short* Vth = Vtb + (size_t)bh * DH * SEQ;

  const int sr = tid >> 3;
  const int sc = 8 * ((tid & 7) ^ (sr & 7));
  const int ksw = (q32 & 7) << 3;

  const short oneb = (short)0x3F80;  // bf16 1.0
  const bf16x8 onesv = {oneb, oneb, oneb, oneb, oneb, oneb, oneb, oneb};

#define ASTAGE(buf, kb0)                                                      \
  do {                                                                        \
    gl2lds16(&Kh[(size_t)((kb0) + sr) * DH + sc], &kl[buf][tid * 8]);         \
    gl2lds16(&Kh[(size_t)((kb0) + sr + 32) * DH + sc], &kl[buf][tid * 8 + 2048]); \
    gl2lds16(&Vth[(size_t)sr * SEQ + (kb0) + sc], &vt[buf][tid * 8]);         \
    gl2lds16(&Vth[(size_t)(sr + 32) * SEQ + (kb0) + sc], &vt[buf][tid * 8 + 2048]); \
  } while (0)

  f32x16 o0 = {}, o1 = {}, ol = {};

  ASTAGE(0, 0);
  __syncthreads();
  const int NT = SEQ / 64;  // 32
#pragma unroll 2
  for (int it = 0; it < NT; ++it) {
    const int cur = it & 1;
    if (it + 1 < NT) ASTAGE(cur ^ 1, (it + 1) * 64);

    f32x16 s0 = {}, s1 = {};
    __builtin_amdgcn_s_setprio(1);
#pragma unroll
    for (int dc = 0; dc < 4; ++dc) {
      const int colb = dc * 16 + hi * 8;
      bf16x8 kf0 = *(const bf16x8*)&kl[cur][q32 * 64 + (colb ^ ksw)];
      bf16x8 kf1 = *(const bf16x8*)&kl[cur][(32 + q32) * 64 + (colb ^ ksw)];
      s0 = MFMA32(kf0, qf[dc], s0);
      s1 = MFMA32(kf1, qf[dc], s1);
    }
    __builtin_amdgcn_s_setprio(0);

#pragma unroll
    for (int r = 0; r < 16; ++r) {
      s0[r] = fexp2(s0[r]);
      s1[r] = fexp2(s1[r]);
    }

    bf16x8 pav[4];
#pragma unroll
    for (int c = 0; c < 4; ++c) {
      const int b = 8 * (c & 1);
      unsigned int wA0, wA1, wB0, wB1;
      if (c < 2) {
        PACKBF(wA0, s0[b + 0], s0[b + 1]); PACKBF(wA1, s0[b + 2], s0[b + 3]);
        PACKBF(wB0, s0[b + 4], s0[b + 5]); PACKBF(wB1, s0[b + 6], s0[b + 7]);
      } else {
        PACKBF(wA0, s1[b + 0], s1[b + 1]); PACKBF(wA1, s1[b + 2], s1[b + 3]);
        PACKBF(wB0, s1[b + 4], s1[b + 5]); PACKBF(wB1, s1[b + 6], s1[b + 7]);
      }
      SWAP32(wA0, wB0);
      SWAP32(wA1, wB1);
      union { unsigned int w[4]; bf16x8 v; } u;
      u.w[0] = wA0; u.w[1] = wA1; u.w[2] = wB0; u.w[3] = wB1;
      pav[c] = u.v;
    }

    __builtin_amdgcn_s_setprio(1);
#pragma unroll
    for (int c = 0; c < 4; ++c) {
      const int colb = c * 16 + hi * 8;
      bf16x8 vf0 = *(const bf16x8*)&vt[cur][q32 * 64 + (colb ^ ksw)];
      bf16x8 vf1 = *(const bf16x8*)&vt[cur][(32 + q32) * 64 + (colb ^ ksw)];
      o0 = MFMA32(pav[c], vf0, o0);
      o1 = MFMA32(pav[c], vf1, o1);
      ol = MFMA32(pav[c], onesv, ol);
    }
    __builtin_amdgcn_s_setprio(0);
    __syncthreads();
  }
#undef ASTAGE

  const int b = bh / NH, h = bh % NH;
#pragma unroll
  for (int r = 0; r < 16; ++r) {
    const int qq = (r & 3) + 8 * (r >> 2) + 4 * hi;
    const float iv = __builtin_amdgcn_rcpf(ol[r]);
    size_t base = ((size_t)(b * SEQ + qbase + qq)) * CD + h * DH;
    Ob[base + q32] = f2bf(o0[r] * iv);
    Ob[base + 32 + q32] = f2bf(o1[r] * iv);
  }
}

// ---------------- Proj GEMM: 128x128 tile, BK=64, swizzled LDS, fp32 out ----------------
__global__ __launch_bounds__(256) void proj_gemm(
    const unsigned short* __restrict__ Ab, const unsigned short* __restrict__ Wb,
    const float* __restrict__ bias, float* __restrict__ out) {
  __shared__ unsigned short Als[2][128 * 64];   // 32KB
  __shared__ unsigned short Bls[2][128 * 64];   // 32KB
  const int tid = threadIdx.x;
  const int wid = tid >> 6, lane = tid & 63;
  const int g = lane >> 4, cl = lane & 15;
  const int bm = blockIdx.x, bn = blockIdx.y;
  const int wr = (wid >> 1) * 64, wc = (wid & 1) * 64;

  f32x4 acc[4][4] = {};

  const int srow = tid >> 3;                      // 0..31
  const int scol = ((tid & 7) ^ (srow & 7)) * 8;
  const unsigned short* Abase = Ab + (size_t)(bm * 128 + srow) * CD + scol;
  const unsigned short* Bbase = Wb + (size_t)(bn * 128 + srow) * CD + scol;

#define PSTG(buf, kt)                                                         \
  do {                                                                        \
    gl2lds16(Abase + (size_t)0 * 32 * CD + (kt) * 64, &Als[buf][0 * 2048 + tid * 8]); \
    gl2lds16(Abase + (size_t)1 * 32 * CD + (kt) * 64, &Als[buf][1 * 2048 + tid * 8]); \
    gl2lds16(Abase + (size_t)2 * 32 * CD + (kt) * 64, &Als[buf][2 * 2048 + tid * 8]); \
    gl2lds16(Abase + (size_t)3 * 32 * CD + (kt) * 64, &Als[buf][3 * 2048 + tid * 8]); \
    gl2lds16(Bbase + (size_t)0 * 32 * CD + (kt) * 64, &Bls[buf][0 * 2048 + tid * 8]); \
    gl2lds16(Bbase + (size_t)1 * 32 * CD + (kt) * 64, &Bls[buf][1 * 2048 + tid * 8]); \
    gl2lds16(Bbase + (size_t)2 * 32 * CD + (kt) * 64, &Bls[buf][2 * 2048 + tid * 8]); \
    gl2lds16(Bbase + (size_t)3 * 32 * CD + (kt) * 64, &Bls[buf][3 * 2048 + tid * 8]); \
  } while (0)

  PSTG(0, 0);
  __syncthreads();
  const int NKT = CD / 64;  // 12
  for (int kt = 0; kt < NKT; ++kt) {
    const int cur = kt & 1;
    if (kt + 1 < NKT) PSTG(cur ^ 1, kt + 1);
    bf16x8 bfr[4][2];
#pragma unroll
    for (int j = 0; j < 4; ++j) {
      const int Bcol = wc + j * 16 + cl;
      const int sw = (Bcol & 7) << 3;
      bfr[j][0] = *(const bf16x8*)&Bls[cur][Bcol * 64 + ((g * 8) ^ sw)];
      bfr[j][1] = *(const bf16x8*)&Bls[cur][Bcol * 64 + ((32 + g * 8) ^ sw)];
    }
    __builtin_amdgcn_s_setprio(1);
#pragma unroll
    for (int i = 0; i < 4; ++i) {
      const int Arow = wr + i * 16 + cl;
      const int sw = (Arow & 7) << 3;
      bf16x8 a0 = *(const bf16x8*)&Als[cur][Arow * 64 + ((g * 8) ^ sw)];
      bf16x8 a1 = *(const bf16x8*)&Als[cur][Arow * 64 + ((32 + g * 8) ^ sw)];
#pragma unroll
      for (int j = 0; j < 4; ++j) {
        acc[i][j] = MFMA(a0, bfr[j][0], acc[i][j]);
        acc[i][j] = MFMA(a1, bfr[j][1], acc[i][j]);
      }
    }
    __builtin_amdgcn_s_setprio(0);
    __syncthreads();
  }
#undef PSTG

  const int j0 = bn * 128 + wc;
  float pb4[4];
#pragma unroll
  for (int j = 0; j < 4; ++j) pb4[j] = bias[j0 + j * 16 + cl];
#pragma unroll
  for (int i = 0; i < 4; ++i) {
#pragma unroll
    for (int r = 0; r < 4; ++r) {
      const int m = bm * 128 + wr + i * 16 + g * 4 + r;
      float* orow = out + (size_t)m * CD + j0;
#pragma unroll
      for (int j = 0; j < 4; ++j) orow[j * 16 + cl] = acc[i][j][r] + pb4[j];
    }
  }
}

extern "C" void kernel_launch(void* const* d_in, const int* in_sizes, int n_in,
                              void* d_out, int out_size, void* d_ws, size_t ws_size,
                              hipStream_t stream) {
  const float* x = (const float*)d_in[0];
  const float* qkv_w = (const float*)d_in[1];
  const float* qkv_b = (const float*)d_in[2];
  const float* proj_w = (const float*)d_in[3];
  const float* proj_b = (const float*)d_in[4];
  const float* q_gamma = (const float*)d_in[5];
  const float* q_beta = (const float*)d_in[6];
  const float* k_gamma = (const float*)d_in[7];
  const float* k_beta = (const float*)d_in[8];
  float* out = (float*)d_out;

  char* w = (char*)d_ws;
  unsigned short* Xb = (unsigned short*)w; w += (size_t)MROWS * CD * 2;
  unsigned short* Wq = (unsigned short*)w; w += (size_t)NQKV * CD * 2;
  unsigned short* Wp = (unsigned short*)w; w += (size_t)CD * CD * 2;
  unsigned short* Qo = (unsigned short*)w; w += (size_t)BB * NH * SEQ * DH * 2;
  unsigned short* Ko = (unsigned short*)w; w += (size_t)BB * NH * SEQ * DH * 2;
  unsigned short* Vt = (unsigned short*)w; w += (size_t)BB * NH * SEQ * DH * 2;  // [b,h,d,n]
  unsigned short* Ob = (unsigned short*)w; w += (size_t)MROWS * CD * 2;

  cvt_bf16<<<MROWS * CD / 1024, 256, 0, stream>>>(x, Xb, MROWS * CD / 4);
  cvt_bf16<<<NQKV * CD / 1024, 256, 0, stream>>>(qkv_w, Wq, NQKV * CD / 4);
  cvt_bf16<<<CD * CD / 1024, 256, 0, stream>>>(proj_w, Wp, CD * CD / 4);

  qkv_gemm<<<(MROWS / 128) * (NQKV / 128), 256, 0, stream>>>(
      Xb, Wq, qkv_b, q_gamma, q_beta, k_gamma, k_beta, Qo, Ko, Vt);

  attn_fwd<<<SEQ / 128 * BB * NH, 256, 0, stream>>>(Qo, Ko, Vt, Ob);

  proj_gemm<<<dim3(MROWS / 128, CD / 128), 256, 0, stream>>>(Ob, Wp, proj_b, out);
}